// Round 6
// baseline (100326.428 us; speedup 1.0000x reference)
//
#include <hip/hip_runtime.h>

#define BB 16
#define SS 128
#define TT 128
#define EE 512
#define HH 512
#define DD 1024
#define VO 10000
#define DNB 512   // decoder: 512 persistent blocks (2 per CU)
#define DNT 512   // 8 waves per block

__device__ __forceinline__ float wred(float s) {
#pragma unroll
  for (int off = 32; off >= 1; off >>= 1) s += __shfl_xor(s, off, 64);
  return s;
}
__device__ __forceinline__ float wmax(float s) {
#pragma unroll
  for (int off = 32; off >= 1; off >>= 1) s = fmaxf(s, __shfl_xor(s, off, 64));
  return s;
}
__device__ __forceinline__ float sigm(float x) { return 1.f / (1.f + expf(-x)); }

// ---- two-level grid barrier. Leaves at [(lb>>3)<<5] (max 64 leaves -> 2048
// uints), root at 2048, gen at 2112. Domain stride 4096 uints. ACQ_REL chain
// leaf->root->gen-release; waiters end with one ACQUIRE of gen. ----
__device__ __forceinline__ void gbar(unsigned* bar, int lb, unsigned nleaf) {
  __syncthreads();
  if (threadIdx.x == 0) {
    unsigned* leaf = bar + ((lb >> 3) << 5);
    unsigned* root = bar + 2048;
    unsigned* gen = bar + 2112;
    const unsigned g = __hip_atomic_load(gen, __ATOMIC_RELAXED, __HIP_MEMORY_SCOPE_AGENT);
    const unsigned a =
        __hip_atomic_fetch_add(leaf, 1u, __ATOMIC_ACQ_REL, __HIP_MEMORY_SCOPE_AGENT);
    if (a == 7u) {
      __hip_atomic_store(leaf, 0u, __ATOMIC_RELAXED, __HIP_MEMORY_SCOPE_AGENT);
      const unsigned r =
          __hip_atomic_fetch_add(root, 1u, __ATOMIC_ACQ_REL, __HIP_MEMORY_SCOPE_AGENT);
      if (r == nleaf - 1u) {
        __hip_atomic_store(root, 0u, __ATOMIC_RELAXED, __HIP_MEMORY_SCOPE_AGENT);
        __hip_atomic_store(gen, g + 1u, __ATOMIC_RELEASE, __HIP_MEMORY_SCOPE_AGENT);
      }
    }
    while (__hip_atomic_load(gen, __ATOMIC_RELAXED, __HIP_MEMORY_SCOPE_AGENT) == g)
      __builtin_amdgcn_s_sleep(16);
    (void)__hip_atomic_load(gen, __ATOMIC_ACQUIRE, __HIP_MEMORY_SCOPE_AGENT);
  }
  __syncthreads();
}

// ---- embedding gather (padding_idx=0 -> zeros), out layout [Sn][B][E] ----
__global__ void gather_k(const int* __restrict__ idx, const float* __restrict__ emb,
                         float* __restrict__ out, int Sn) {
  const int s = blockIdx.x, b = blockIdx.y, tid = threadIdx.x;
  const int id = idx[b * Sn + s];
  float4 v = make_float4(0.f, 0.f, 0.f, 0.f);
  if (id != 0) v = ((const float4*)(emb + (size_t)id * EE))[tid];
  ((float4*)(out + ((size_t)s * BB + b) * EE))[tid] = v;
}

// ---- G[z][n][m] = sum_k X[m,k]*W[z,n,k]  (x-part gate GEMMs, parallel) ----
template <int K>
__global__ void gemv16_k(const float* __restrict__ X, int ldx,
                         const float* __restrict__ W, int ldw,
                         float* __restrict__ G, int M, size_t wz, size_t gz) {
  const int lane = threadIdx.x & 63;
  const int n = blockIdx.x * 4 + (threadIdx.x >> 6);
  const int mg = blockIdx.y;
  const int z = blockIdx.z;
  const float* Xr = X + (size_t)mg * 16 * ldx;
  const float* Wn = W + (size_t)z * wz + (size_t)n * ldw;
  float acc[16];
#pragma unroll
  for (int j = 0; j < 16; ++j) acc[j] = 0.f;
  for (int kb = 0; kb < K / 64; ++kb) {
    const int k = kb * 64 + lane;
    const float wv = Wn[k];
#pragma unroll
    for (int j = 0; j < 16; ++j) acc[j] = fmaf(wv, Xr[(size_t)j * ldx + k], acc[j]);
  }
#pragma unroll
  for (int j = 0; j < 16; ++j) acc[j] = wred(acc[j]);
  float sel = 0.f;
#pragma unroll
  for (int j = 0; j < 16; ++j)
    if (lane == j) sel = acc[j];
  if (lane < 16) G[(size_t)z * gz + (size_t)n * M + mg * 16 + lane] = sel;
}

// ---- persistent encoder layer: 256 blocks x 512 thr, whh in VGPRs ----
__global__ __launch_bounds__(512, 1) void enc_mega3_k(
    const float* __restrict__ gx, const float* __restrict__ whh,
    const float* __restrict__ bias, float* __restrict__ hbuf, float* __restrict__ seq,
    int seq_ts, int seq_bs, unsigned* __restrict__ barbase) {
  const int tid = threadIdx.x, lane = tid & 63, lw = tid >> 6;
  const int gw = blockIdx.x * 8 + lw;  // 0..2047
  const int dir = gw >> 10, r = gw & 1023;
  const int d = r >> 1, gp = r & 1;  // even wave: gates 0(i),2(g); odd: 1(f),3(o)
  const int g0 = gp, g1 = gp + 2;
  const int pair = lw >> 1;
  unsigned* bar = barbase + dir * 4096;
  const int lb = blockIdx.x & 127;  // block index within dir

  __shared__ float xch[4][4][16];

  float wa[8], wb[8];
  const float* wsrc = whh + (size_t)dir * (4 * HH * HH);
#pragma unroll
  for (int j = 0; j < 8; ++j) {
    wa[j] = wsrc[(size_t)(g0 * HH + d) * HH + j * 64 + lane];
    wb[j] = wsrc[(size_t)(g1 * HH + d) * HH + j * 64 + lane];
  }
#pragma unroll
  for (int j = 0; j < 8; ++j) {
    asm volatile("" : "+v"(wa[j]));
    asm volatile("" : "+v"(wb[j]));
  }
  const float bv0 = bias[dir * 4 * HH + g0 * HH + d];
  const float bv1 = bias[dir * 4 * HH + g1 * HH + d];
  const float* gxz = gx + (size_t)dir * ((size_t)4 * HH * 2048);
  float creg = 0.f;

  for (int t = 0; t < SS; ++t) {
    const int idx = dir ? (SS - 1 - t) : t;
    const float* hp = hbuf + (t & 1) * (2 * BB * HH) + dir * (BB * HH);
    float* hn = hbuf + ((t & 1) ^ 1) * (2 * BB * HH) + dir * (BB * HH);
    float a0[16], a1[16];
#pragma unroll
    for (int b = 0; b < 16; ++b) { a0[b] = 0.f; a1[b] = 0.f; }
#pragma unroll
    for (int kb = 0; kb < 8; ++kb) {
      const int k = kb * 64 + lane;
#pragma unroll
      for (int b = 0; b < 16; ++b) {
        const float xv = hp[b * HH + k];
        a0[b] = fmaf(wa[kb], xv, a0[b]);
        a1[b] = fmaf(wb[kb], xv, a1[b]);
      }
    }
#pragma unroll
    for (int b = 0; b < 16; ++b) { a0[b] = wred(a0[b]); a1[b] = wred(a1[b]); }
    float s0 = 0.f, s1 = 0.f;
#pragma unroll
    for (int j = 0; j < 16; ++j)
      if (lane == j) { s0 = a0[j]; s1 = a1[j]; }
    if (lane < 16) {
      const int m = idx * 16 + lane;
      xch[pair][g0][lane] = s0 + bv0 + gxz[(size_t)(g0 * HH + d) * 2048 + m];
      xch[pair][g1][lane] = s1 + bv1 + gxz[(size_t)(g1 * HH + d) * 2048 + m];
    }
    __syncthreads();
    if (gp == 0 && lane < 16) {
      const float gi = sigm(xch[pair][0][lane]);
      const float gf = sigm(xch[pair][1][lane]);
      const float gg = tanhf(xch[pair][2][lane]);
      const float go = sigm(xch[pair][3][lane]);
      const float cn = gf * creg + gi * gg;
      creg = cn;
      const float hv = go * tanhf(cn);
      hn[lane * HH + d] = hv;
      seq[(size_t)idx * seq_ts + (size_t)lane * seq_bs + dir * HH + d] = hv;
    }
    gbar(bar, lb, 16u);
  }
}

// ---- persistent decoder: 512 blocks x 512 thr, one wave per (gate,d) row ----
// Per-thread resident: w0[40] + w1[32] = 72 floats  ->  fits the 128-VGPR cap.
__global__ __launch_bounds__(512, 4) void dec_mega4_k(
    const float* __restrict__ gs_emb, const float* __restrict__ encWe,
    const float* __restrict__ enc_out, const float* __restrict__ attn_w,
    const float* __restrict__ attn_b, const float* __restrict__ attn_v,
    const float* __restrict__ wih0, const float* __restrict__ whh0,
    const float* __restrict__ b0, const float* __restrict__ wih1,
    const float* __restrict__ whh1, const float* __restrict__ b1,
    const float* __restrict__ zeros, float* __restrict__ dh0, float* __restrict__ h1p,
    float* __restrict__ c1g, float* __restrict__ h1_all, float* __restrict__ qWg,
    float* __restrict__ scoresg, float* __restrict__ wtd, unsigned* __restrict__ bar) {
  const int tid = threadIdx.x, lane = tid & 63, lw = tid >> 6;
  const int gw = blockIdx.x * 8 + lw;  // 0..4095
  const int g = gw & 3;                // gate (i,f,g,o)
  const int d = gw >> 2;               // hidden unit 0..1023
  const int pr = (lw >> 2) & 1;        // which of the block's 2 d's
  const bool gzero = (g == 0);
  const int b_a = blockIdx.x >> 5, jb = blockIdx.x & 31;  // attention mapping

  __shared__ float encWe_s[4][1024];  // s-rows jb*4..+3 of batch b_a (16KB)
  __shared__ float enc_s[128][33];    // enc_out[b_a][all s][jb*32..+31] (16.9KB)
  __shared__ float av_s[1024];        // attn_v (4KB)
  __shared__ float xch[2][4][16];     // gate exchange

  // ---- resident weights: row (g*1024+d) of each matrix ----
  float w0[40], w1[32];
#pragma unroll
  for (int kb = 0; kb < 24; ++kb)
    w0[kb] = wih0[(size_t)(g * DD + d) * 1536 + kb * 64 + lane];
#pragma unroll
  for (int kb = 0; kb < 16; ++kb)
    w0[24 + kb] = whh0[(size_t)(g * DD + d) * 1024 + kb * 64 + lane];
#pragma unroll
  for (int kb = 0; kb < 16; ++kb)
    w1[kb] = wih1[(size_t)(g * DD + d) * 1024 + kb * 64 + lane];
#pragma unroll
  for (int kb = 0; kb < 16; ++kb)
    w1[16 + kb] = whh1[(size_t)(g * DD + d) * 1024 + kb * 64 + lane];
#pragma unroll
  for (int i = 0; i < 40; ++i) asm volatile("" : "+v"(w0[i]));
#pragma unroll
  for (int i = 0; i < 32; ++i) asm volatile("" : "+v"(w1[i]));
  const float bd0 = b0[g * DD + d];
  const float bd1 = b1[g * DD + d];
  const float abv = attn_b[d];
  float c0reg = 0.f, c1reg = 0.f;

  // ---- LDS fill (read-only for the whole decode) ----
  for (int i = tid; i < 4 * 1024; i += DNT)
    encWe_s[i >> 10][i & 1023] =
        encWe[((size_t)(b_a * SS + jb * 4 + (i >> 10))) * 1024 + (i & 1023)];
  for (int i = tid; i < 128 * 32; i += DNT)
    enc_s[i >> 5][i & 31] = enc_out[((size_t)(b_a * SS + (i >> 5))) * 1024 + jb * 32 + (i & 31)];
  for (int i = tid; i < 1024; i += DNT) av_s[i] = attn_v[i];
  __syncthreads();

  // ---- priming: layer0 gates = biases (zero input & state) ----
  if (gzero && lane < 16) {
    const float gi = sigm(b0[0 * DD + d]);
    const float gf = sigm(b0[1 * DD + d]);
    const float gg = tanhf(b0[2 * DD + d]);
    const float go = sigm(b0[3 * DD + d]);
    const float cn = gf * 0.f + gi * gg;
    c0reg = cn;
    dh0[lane * 1024 + d] = go * tanhf(cn);  // slot 0
  }
  gbar(bar, blockIdx.x, 64u);
  {  // priming layer 1: input = primed h0 (slot 0), h1prev = zeros
#pragma unroll 1
    for (int half = 0; half < 2; ++half) {
      float acc[8];
#pragma unroll
      for (int j = 0; j < 8; ++j) acc[j] = 0.f;
#pragma unroll
      for (int kb = 0; kb < 16; ++kb) {
        const int k = kb * 64 + lane;
#pragma unroll
        for (int j = 0; j < 8; ++j)
          acc[j] = fmaf(w1[kb], dh0[(half * 8 + j) * 1024 + k], acc[j]);
      }
#pragma unroll
      for (int j = 0; j < 8; ++j) acc[j] = wred(acc[j]);
      float sel = 0.f;
#pragma unroll
      for (int j = 0; j < 8; ++j)
        if (lane == j) sel = acc[j];
      if (lane < 8) xch[pr][g][half * 8 + lane] = sel + bd1;
    }
    __syncthreads();
    if (gzero && lane < 16) {
      const float gi = sigm(xch[pr][0][lane]);
      const float gf = sigm(xch[pr][1][lane]);
      const float gg = tanhf(xch[pr][2][lane]);
      const float go = sigm(xch[pr][3][lane]);
      const float cn = gf * c1reg + gi * gg;
      c1reg = cn;
      c1g[lane * 1024 + d] = cn;
      h1p[lane * 1024 + d] = go * tanhf(cn);
    }
  }
  gbar(bar, blockIdx.x, 64u);

  // ---- decode loop: 5 barriers per step ----
  for (int t = 0; t < TT; ++t) {
    {  // qW[b,d]: wave (d, bq=g) handles 4 batches; attn_w streamed (L3-hot)
      const int bq = g;
      float acc[4];
#pragma unroll
      for (int j = 0; j < 4; ++j) acc[j] = 0.f;
#pragma unroll
      for (int kb = 0; kb < 16; ++kb) {
        const int k = kb * 64 + lane;
        const float wv = attn_w[(size_t)d * 2048 + k];
#pragma unroll
        for (int j = 0; j < 4; ++j)
          acc[j] = fmaf(wv, c1g[(bq * 4 + j) * 1024 + k], acc[j]);
      }
#pragma unroll
      for (int j = 0; j < 4; ++j) acc[j] = wred(acc[j]);
      float sel = 0.f;
#pragma unroll
      for (int j = 0; j < 4; ++j)
        if (lane == j) sel = acc[j];
      if (lane < 4) qWg[(bq * 4 + lane) * 1024 + d] = sel + abv;
    }
    gbar(bar, blockIdx.x, 64u);
    if (lw < 4) {  // scores[b_a, jb*4+lw]
      const int sj = jb * 4 + lw;
      float a = 0.f;
#pragma unroll
      for (int kb = 0; kb < 16; ++kb) {
        const int k = kb * 64 + lane;
        a += av_s[k] * tanhf(qWg[b_a * 1024 + k] + encWe_s[lw][k]);
      }
      a = wred(a);
      if (lane == 0) scoresg[b_a * SS + sj] = a;
    }
    gbar(bar, blockIdx.x, 64u);
    {  // softmax + weighted sum for h-cols jb*32..+31 of batch b_a
      const float sc0 = scoresg[b_a * SS + lane];
      const float sc1 = scoresg[b_a * SS + 64 + lane];
      const float m = wmax(fmaxf(sc0, sc1));
      const float e0 = expf(sc0 - m), e1 = expf(sc1 - m);
      const float inv = 1.f / wred(e0 + e1);
#pragma unroll
      for (int cc = 0; cc < 4; ++cc) {
        const int col = lw * 4 + cc;
        float p = e0 * enc_s[lane][col] + e1 * enc_s[64 + lane][col];
        p = wred(p);
        if (lane == 0) wtd[b_a * 1024 + jb * 32 + col] = p * inv;
      }
    }
    gbar(bar, blockIdx.x, 64u);
    {  // decoder layer 0: K = wtd(1024) + emb(512) + h0prev(1024)
      const float* em = t ? gs_emb + (size_t)(t - 1) * BB * EE : zeros;
      const float* hp = dh0 + (t & 1) * (BB * DD);
#pragma unroll 1
      for (int half = 0; half < 2; ++half) {
        float acc[8];
#pragma unroll
        for (int j = 0; j < 8; ++j) acc[j] = 0.f;
#pragma unroll
        for (int kb = 0; kb < 16; ++kb) {
          const int k = kb * 64 + lane;
#pragma unroll
          for (int j = 0; j < 8; ++j)
            acc[j] = fmaf(w0[kb], wtd[(half * 8 + j) * 1024 + k], acc[j]);
        }
#pragma unroll
        for (int kb = 0; kb < 8; ++kb) {
          const int k = kb * 64 + lane;
#pragma unroll
          for (int j = 0; j < 8; ++j)
            acc[j] = fmaf(w0[16 + kb], em[(half * 8 + j) * 512 + k], acc[j]);
        }
#pragma unroll
        for (int kb = 0; kb < 16; ++kb) {
          const int k = kb * 64 + lane;
#pragma unroll
          for (int j = 0; j < 8; ++j)
            acc[j] = fmaf(w0[24 + kb], hp[(half * 8 + j) * 1024 + k], acc[j]);
        }
#pragma unroll
        for (int j = 0; j < 8; ++j) acc[j] = wred(acc[j]);
        float sel = 0.f;
#pragma unroll
        for (int j = 0; j < 8; ++j)
          if (lane == j) sel = acc[j];
        if (lane < 8) xch[pr][g][half * 8 + lane] = sel + bd0;
      }
      __syncthreads();
      if (gzero && lane < 16) {
        const float gi = sigm(xch[pr][0][lane]);
        const float gf = sigm(xch[pr][1][lane]);
        const float gg = tanhf(xch[pr][2][lane]);
        const float go = sigm(xch[pr][3][lane]);
        const float cn = gf * c0reg + gi * gg;
        c0reg = cn;
        dh0[((t & 1) ^ 1) * (BB * DD) + lane * 1024 + d] = go * tanhf(cn);
      }
    }
    gbar(bar, blockIdx.x, 64u);
    {  // decoder layer 1: K = h0(1024) + h1prev(1024)
      const float* h0 = dh0 + ((t & 1) ^ 1) * (BB * DD);
      const float* h1prev = t ? h1_all + (size_t)(t - 1) * (BB * DD) : h1p;
#pragma unroll 1
      for (int half = 0; half < 2; ++half) {
        float acc[8];
#pragma unroll
        for (int j = 0; j < 8; ++j) acc[j] = 0.f;
#pragma unroll
        for (int kb = 0; kb < 16; ++kb) {
          const int k = kb * 64 + lane;
#pragma unroll
          for (int j = 0; j < 8; ++j)
            acc[j] = fmaf(w1[kb], h0[(half * 8 + j) * 1024 + k], acc[j]);
        }
#pragma unroll
        for (int kb = 0; kb < 16; ++kb) {
          const int k = kb * 64 + lane;
#pragma unroll
          for (int j = 0; j < 8; ++j)
            acc[j] = fmaf(w1[16 + kb], h1prev[(half * 8 + j) * 1024 + k], acc[j]);
        }
#pragma unroll
        for (int j = 0; j < 8; ++j) acc[j] = wred(acc[j]);
        float sel = 0.f;
#pragma unroll
        for (int j = 0; j < 8; ++j)
          if (lane == j) sel = acc[j];
        if (lane < 8) xch[pr][g][half * 8 + lane] = sel + bd1;
      }
      __syncthreads();
      if (gzero && lane < 16) {
        const float gi = sigm(xch[pr][0][lane]);
        const float gf = sigm(xch[pr][1][lane]);
        const float gg = tanhf(xch[pr][2][lane]);
        const float go = sigm(xch[pr][3][lane]);
        const float cn = gf * c1reg + gi * gg;
        c1reg = cn;
        c1g[lane * 1024 + d] = cn;
        h1_all[(size_t)t * (BB * DD) + lane * 1024 + d] = go * tanhf(cn);
      }
    }
    gbar(bar, blockIdx.x, 64u);
  }
}

// ---- encWe[m][n] = sum_k enc_out[m][k]*attn_w[n][1024+k], LDS-staged X ----
__global__ __launch_bounds__(512) void encwe2_k(const float* __restrict__ enc_out,
                                                const float* __restrict__ attn_w,
                                                float* __restrict__ encWe) {
  const int tid = threadIdx.x, lane = tid & 63, lw = tid >> 6;
  const int mg = blockIdx.x;  // rows m = mg*16..+15  (m = b*128+s)
  const int nq = blockIdx.y;  // n = nq*64..+63
  __shared__ float xs[16][1024];
  for (int i = tid; i < 16 * 1024; i += 512)
    xs[i >> 10][i & 1023] = enc_out[((size_t)mg * 16 + (i >> 10)) * 1024 + (i & 1023)];
  __syncthreads();
#pragma unroll 1
  for (int nn = 0; nn < 8; ++nn) {
    const int n = nq * 64 + lw * 8 + nn;
    float acc[16];
#pragma unroll
    for (int j = 0; j < 16; ++j) acc[j] = 0.f;
#pragma unroll
    for (int kb = 0; kb < 16; ++kb) {
      const int k = kb * 64 + lane;
      const float wv = attn_w[(size_t)n * 2048 + 1024 + k];
#pragma unroll
      for (int j = 0; j < 16; ++j) acc[j] = fmaf(wv, xs[j][k], acc[j]);
    }
#pragma unroll
    for (int j = 0; j < 16; ++j) acc[j] = wred(acc[j]);
    float sel = 0.f;
#pragma unroll
    for (int j = 0; j < 16; ++j)
      if (lane == j) sel = acc[j];
    if (lane < 16) encWe[((size_t)mg * 16 + lane) * 1024 + n] = sel;
  }
}

// ---- all logits at the end ----
__global__ void logits_all_k(const float* __restrict__ h1all, const float* __restrict__ out_w,
                             const float* __restrict__ out_b, float* __restrict__ out) {
  const int lane = threadIdx.x & 63;
  const int t = blockIdx.x;
  const int o = blockIdx.y * 4 + (threadIdx.x >> 6);
  const float* h1 = h1all + (size_t)t * (BB * DD);
  float acc[16];
#pragma unroll
  for (int b = 0; b < 16; ++b) acc[b] = 0.f;
  for (int kb = 0; kb < 16; ++kb) {
    const int k = kb * 64 + lane;
    const float wv = out_w[(size_t)o * DD + k];
#pragma unroll
    for (int b = 0; b < 16; ++b) acc[b] = fmaf(wv, h1[b * DD + k], acc[b]);
  }
#pragma unroll
  for (int b = 0; b < 16; ++b) acc[b] = wred(acc[b]);
  float sel = 0.f;
#pragma unroll
  for (int b = 0; b < 16; ++b)
    if (lane == b) sel = acc[b];
  if (lane < 16) out[(size_t)lane * TT * VO + (size_t)t * VO + o] = sel + out_b[o];
}

extern "C" void kernel_launch(void* const* d_in, const int* in_sizes, int n_in,
                              void* d_out, int out_size, void* d_ws, size_t ws_size,
                              hipStream_t stream) {
  const int* x = (const int*)d_in[0];
  const int* gs = (const int*)d_in[1];
  const float* in_emb = (const float*)d_in[2];
  const float* out_emb = (const float*)d_in[3];
  const float* ewih0 = (const float*)d_in[4];
  const float* ewhh0 = (const float*)d_in[5];
  const float* eb0 = (const float*)d_in[6];
  const float* ewih1 = (const float*)d_in[7];
  const float* ewhh1 = (const float*)d_in[8];
  const float* eb1 = (const float*)d_in[9];
  const float* dwih0 = (const float*)d_in[10];
  const float* dwhh0 = (const float*)d_in[11];
  const float* db0 = (const float*)d_in[12];
  const float* dwih1 = (const float*)d_in[13];
  const float* dwhh1 = (const float*)d_in[14];
  const float* db1 = (const float*)d_in[15];
  const float* attn_w = (const float*)d_in[16];
  const float* attn_b = (const float*)d_in[17];
  const float* attn_v = (const float*)d_in[18];
  const float* out_w = (const float*)d_in[19];
  const float* out_b = (const float*)d_in[20];
  float* out = (float*)d_out;

  float* ws = (float*)d_ws;
  size_t off = 0;
  auto alloc = [&](size_t n) { float* p = ws + off; off += n; return p; };
  // ---- memset-every-call region ----
  unsigned* bar = (unsigned*)alloc(3 * 4096);    // 3 barrier domains (encd0/encd1/dec)
  float* h0e = alloc(2 * 2 * BB * HH);           // enc L0 h ping-pong
  float* h1e = alloc(2 * 2 * BB * HH);           // enc L1
  float* dh0 = alloc(2 * BB * DD);               // dec L0 h ping-pong
  float* dh1p = alloc(BB * DD);                  // primed dec L1 h
  float* dc1g = alloc(BB * DD);                  // dec L1 c (global copy for qw)
  float* zeros = alloc(BB * DD);
  const size_t state_n = off;
  // ---- fully-overwritten buffers ----
  float* xs_emb = alloc((size_t)SS * BB * EE);
  float* gs_emb = alloc((size_t)TT * BB * EE);
  float* l0 = alloc((size_t)SS * BB * (2 * HH));
  float* enc_out = alloc((size_t)BB * SS * (2 * HH));
  float* encWe = alloc((size_t)BB * SS * DD);
  float* gxA = alloc(2ull * 2048ull * 2048ull);  // x-part gates, reused L0/L1
  float* h1_all = alloc((size_t)TT * BB * DD);
  float* qW = alloc(BB * DD);
  float* scores = alloc(BB * SS);
  float* wtd = alloc(BB * DD);
  (void)ws_size; (void)in_sizes; (void)n_in; (void)out_size;

  hipMemsetAsync(d_ws, 0, state_n * sizeof(float), stream);

  gather_k<<<dim3(SS, BB), 128, 0, stream>>>(x, in_emb, xs_emb, SS);
  gather_k<<<dim3(TT, BB), 128, 0, stream>>>(gs, out_emb, gs_emb, TT);

  // encoder layer 0: parallel x-part, then persistent recurrence
  gemv16_k<EE><<<dim3(512, 128, 2), 256, 0, stream>>>(
      xs_emb, EE, ewih0, EE, gxA, 2048, (size_t)4 * HH * EE, 2048ull * 2048ull);
  enc_mega3_k<<<256, 512, 0, stream>>>(gxA, ewhh0, eb0, h0e, l0, BB * 2 * HH, 2 * HH, bar);
  // encoder layer 1
  gemv16_k<2 * HH><<<dim3(512, 128, 2), 256, 0, stream>>>(
      l0, 2 * HH, ewih1, 2 * HH, gxA, 2048, (size_t)4 * HH * 2 * HH, 2048ull * 2048ull);
  enc_mega3_k<<<256, 512, 0, stream>>>(gxA, ewhh1, eb1, h1e, enc_out, 2 * HH, SS * 2 * HH,
                                       bar);
  // step-invariant attention term (LDS-staged, low redundancy)
  encwe2_k<<<dim3(128, 16), 512, 0, stream>>>(enc_out, attn_w, encWe);

  // persistent decoder (prime + 128 steps)
  dec_mega4_k<<<DNB, DNT, 0, stream>>>(gs_emb, encWe, enc_out, attn_w, attn_b, attn_v,
                                       dwih0, dwhh0, db0, dwih1, dwhh1, db1, zeros, dh0,
                                       dh1p, dc1g, h1_all, qW, scores, wtd, bar + 2 * 4096);

  // all logits in one parallel launch
  logits_all_k<<<dim3(TT, VO / 4), 256, 0, stream>>>(h1_all, out_w, out_b, out);
}

// Round 7
// 24120.892 us; speedup vs baseline: 4.1593x; 4.1593x over previous
//
#include <hip/hip_runtime.h>

#define BB 16
#define SS 128
#define TT 128
#define EE 512
#define HH 512
#define DD 1024
#define VO 10000

__device__ __forceinline__ float wred(float s) {
#pragma unroll
  for (int off = 32; off >= 1; off >>= 1) s += __shfl_xor(s, off, 64);
  return s;
}
__device__ __forceinline__ float sigm(float x) { return 1.f / (1.f + expf(-x)); }

// write-through store / L2-bypass load (agent-scope relaxed atomics -> sc1)
__device__ __forceinline__ void stv(float* p, float v) {
  __hip_atomic_store(p, v, __ATOMIC_RELAXED, __HIP_MEMORY_SCOPE_AGENT);
}
__device__ __forceinline__ float ldv(const float* p) {
  return __hip_atomic_load(p, __ATOMIC_RELAXED, __HIP_MEMORY_SCOPE_AGENT);
}

// ---- grid barrier: RELAXED monotonic counters, NO acquire (no L2 inv). ----
// Every thread drains its own stores (vmcnt) before arrival; producers use
// write-through stv(); consumers read write-once buffers (first-touch) or ldv().
// Domain layout (uints): leaves at (leaf_id<<5), root at 2048, gen at 2112.
__device__ __forceinline__ void gbar(unsigned* bar, int lb, unsigned nleaf) {
  asm volatile("s_waitcnt vmcnt(0) lgkmcnt(0)" ::: "memory");
  __syncthreads();
  if (threadIdx.x == 0) {
    unsigned* leaf = bar + ((lb >> 3) << 5);
    unsigned* root = bar + 2048;
    unsigned* gen = bar + 2112;
    const unsigned g = __hip_atomic_load(gen, __ATOMIC_RELAXED, __HIP_MEMORY_SCOPE_AGENT);
    const unsigned a =
        __hip_atomic_fetch_add(leaf, 1u, __ATOMIC_RELAXED, __HIP_MEMORY_SCOPE_AGENT);
    if (a == g * 8u + 7u) {
      const unsigned r =
          __hip_atomic_fetch_add(root, 1u, __ATOMIC_RELAXED, __HIP_MEMORY_SCOPE_AGENT);
      if (r == g * nleaf + (nleaf - 1u))
        __hip_atomic_store(gen, g + 1u, __ATOMIC_RELAXED, __HIP_MEMORY_SCOPE_AGENT);
    }
    while (__hip_atomic_load(gen, __ATOMIC_RELAXED, __HIP_MEMORY_SCOPE_AGENT) == g)
      __builtin_amdgcn_s_sleep(1);
  }
  __syncthreads();
}

// ---- embedding gather (padding_idx=0 -> zeros), out layout [Sn][B][E] ----
__global__ void gather_k(const int* __restrict__ idx, const float* __restrict__ emb,
                         float* __restrict__ out, int Sn) {
  const int s = blockIdx.x, b = blockIdx.y, tid = threadIdx.x;
  const int id = idx[b * Sn + s];
  float4 v = make_float4(0.f, 0.f, 0.f, 0.f);
  if (id != 0) v = ((const float4*)(emb + (size_t)id * EE))[tid];
  ((float4*)(out + ((size_t)s * BB + b) * EE))[tid] = v;
}

// ---- G[z][n][m] = sum_k X[m,k]*W[z,n,k]  (x-part gate GEMMs, parallel) ----
template <int K>
__global__ void gemv16_k(const float* __restrict__ X, int ldx,
                         const float* __restrict__ W, int ldw,
                         float* __restrict__ G, int M, size_t wz, size_t gz) {
  const int lane = threadIdx.x & 63;
  const int n = blockIdx.x * 4 + (threadIdx.x >> 6);
  const int mg = blockIdx.y;
  const int z = blockIdx.z;
  const float* Xr = X + (size_t)mg * 16 * ldx;
  const float* Wn = W + (size_t)z * wz + (size_t)n * ldw;
  float acc[16];
#pragma unroll
  for (int j = 0; j < 16; ++j) acc[j] = 0.f;
  for (int kb = 0; kb < K / 64; ++kb) {
    const int k = kb * 64 + lane;
    const float wv = Wn[k];
#pragma unroll
    for (int j = 0; j < 16; ++j) acc[j] = fmaf(wv, Xr[(size_t)j * ldx + k], acc[j]);
  }
#pragma unroll
  for (int j = 0; j < 16; ++j) acc[j] = wred(acc[j]);
  float sel = 0.f;
#pragma unroll
  for (int j = 0; j < 16; ++j)
    if (lane == j) sel = acc[j];
  if (lane < 16) G[(size_t)z * gz + (size_t)n * M + mg * 16 + lane] = sel;
}

// ---- persistent encoder layer: 256 blocks x 512 thr ----
// h ping-pong via stv/ldv (bypass); whh in 16 regs/thread; 1 barrier/step.
__global__ __launch_bounds__(512, 2) void enc_mega5_k(
    const float* __restrict__ gx, const float* __restrict__ whh,
    const float* __restrict__ bias, float* __restrict__ hbuf,  // [2][2][16][512]
    float* __restrict__ seq, int seq_ts, int seq_bs, unsigned* __restrict__ barbase) {
  const int tid = threadIdx.x, lane = tid & 63, lw = tid >> 6;
  const int dir = blockIdx.x >> 7;
  const int lb = blockIdx.x & 127;
  const int w2 = lb * 8 + lw;  // wave within dir [0,1024)
  const int d = w2 >> 1, gp = w2 & 1;
  const int g0 = gp, g1 = gp + 2;
  const int pair = lw >> 1;
  unsigned* bar = barbase + dir * 4096;

  __shared__ float hs[16][512];
  __shared__ float xch[4][4][16];

  float wa[8], wb[8];
  const float* wsrc = whh + (size_t)dir * (4 * HH * HH);
#pragma unroll
  for (int j = 0; j < 8; ++j) {
    wa[j] = wsrc[(size_t)(g0 * HH + d) * HH + j * 64 + lane];
    wb[j] = wsrc[(size_t)(g1 * HH + d) * HH + j * 64 + lane];
  }
  const float bv0 = bias[dir * 4 * HH + g0 * HH + d];
  const float bv1 = bias[dir * 4 * HH + g1 * HH + d];
  const float* gxz = gx + (size_t)dir * ((size_t)4 * HH * 2048);
  float creg = 0.f;

  for (int t = 0; t < SS; ++t) {
    const int idx = dir ? (SS - 1 - t) : t;
    const float* hp = hbuf + ((size_t)(t & 1) * 2 + dir) * (BB * HH);
    for (int i = tid; i < BB * HH; i += 512) ((float*)hs)[i] = ldv(hp + i);
    __syncthreads();
    float a0[16], a1[16];
#pragma unroll
    for (int b = 0; b < 16; ++b) { a0[b] = 0.f; a1[b] = 0.f; }
#pragma unroll
    for (int kb = 0; kb < 8; ++kb) {
      const int k = kb * 64 + lane;
#pragma unroll
      for (int b = 0; b < 16; ++b) {
        const float xv = hs[b][k];
        a0[b] = fmaf(wa[kb], xv, a0[b]);
        a1[b] = fmaf(wb[kb], xv, a1[b]);
      }
    }
#pragma unroll
    for (int b = 0; b < 16; ++b) { a0[b] = wred(a0[b]); a1[b] = wred(a1[b]); }
    float s0 = 0.f, s1 = 0.f;
#pragma unroll
    for (int j = 0; j < 16; ++j)
      if (lane == j) { s0 = a0[j]; s1 = a1[j]; }
    if (lane < 16) {
      const int m = idx * 16 + lane;
      xch[pair][g0][lane] = s0 + bv0 + gxz[(size_t)(g0 * HH + d) * 2048 + m];
      xch[pair][g1][lane] = s1 + bv1 + gxz[(size_t)(g1 * HH + d) * 2048 + m];
    }
    __syncthreads();
    if (gp == 0 && lane < 16) {
      const float gi = sigm(xch[pair][0][lane]);
      const float gf = sigm(xch[pair][1][lane]);
      const float gg = tanhf(xch[pair][2][lane]);
      const float go = sigm(xch[pair][3][lane]);
      const float cn = gf * creg + gi * gg;
      creg = cn;
      const float hv = go * tanhf(cn);
      stv(hbuf + ((size_t)((t + 1) & 1) * 2 + dir) * (BB * HH) + lane * HH + d, hv);
      seq[(size_t)idx * seq_ts + (size_t)lane * seq_bs + dir * HH + d] = hv;
    }
    gbar(bar, lb, 16u);
  }
}

// ---- decoder helpers ----
template <int CW>
__device__ __forceinline__ void stagex(float (&xs)[16][1024], const float* __restrict__ src,
                                       int tid) {
#pragma unroll
  for (int i = tid; i < 16 * CW / 4; i += 1024) {
    const int e = i * 4;
    *(float4*)&xs[e / CW][e % CW] = *(const float4*)&src[e];
  }
}

template <int NKB>
__device__ __forceinline__ void gemv_phase(const float* __restrict__ wr0,
                                           const float* __restrict__ wr1,
                                           const float (&xs)[16][1024], int bh, int lane,
                                           float (&a0)[8], float (&a1)[8]) {
#pragma unroll
  for (int kb = 0; kb < NKB; ++kb) {
    const int k = kb * 64 + lane;
    const float wA = wr0[k];
    const float wB = wr1[k];
#pragma unroll
    for (int j = 0; j < 8; ++j) {
      const float xv = xs[bh * 8 + j][k];
      a0[j] = fmaf(wA, xv, a0[j]);
      a1[j] = fmaf(wB, xv, a1[j]);
    }
  }
}

__device__ __forceinline__ void red_xch(float (&a0)[8], float (&a1)[8],
                                        float (&xch)[4][4][16], int dl, int g0, int bh,
                                        int lane) {
#pragma unroll
  for (int j = 0; j < 8; ++j) { a0[j] = wred(a0[j]); a1[j] = wred(a1[j]); }
  float s0 = 0.f, s1 = 0.f;
#pragma unroll
  for (int j = 0; j < 8; ++j)
    if (lane == j) { s0 = a0[j]; s1 = a1[j]; }
  if (lane < 8) {
    xch[dl][g0][bh * 8 + lane] = s0;
    xch[dl][g0 + 1][bh * 8 + lane] = s1;
  }
}

// ---- persistent decoder: 256 blocks x 1024 thr ----
// wave = 2 gate-rows x 8 batches; x LDS-staged; weights stream via warm L1/L2;
// cross-step state in per-t write-once buffers; 5 barriers/step.
__global__ __launch_bounds__(1024, 4) void dec_mega5_k(
    const float* __restrict__ gs_emb, const float* __restrict__ encWe,
    const float* __restrict__ enc_out, const float* __restrict__ attn_w,
    const float* __restrict__ attn_b, const float* __restrict__ attn_v,
    const float* __restrict__ wih0, const float* __restrict__ whh0,
    const float* __restrict__ b0, const float* __restrict__ wih1,
    const float* __restrict__ whh1, const float* __restrict__ b1,
    const float* __restrict__ zeros, float* __restrict__ h0_all,
    float* __restrict__ h1_all, float* __restrict__ c1_all, float* __restrict__ wtd_all,
    float* __restrict__ qWbuf, float* __restrict__ scores_all,
    unsigned* __restrict__ bar) {
  const int tid = threadIdx.x, lane = tid & 63, lw = tid >> 6;
  const int blk = blockIdx.x;
  const int w = blk * 16 + lw;  // 0..4095
  const int d = w >> 2;         // hidden unit
  const int sub = w & 3;
  const int g0 = (sub >> 1) * 2;  // gates {0,1} or {2,3}
  const int bh = sub & 1;         // batch half
  const int dl = lw >> 2;         // d-local 0..3
  const bool owner = (sub == 0);
  const int b_att = blk >> 4, shard = blk & 15;

  __shared__ float xs[16][1024];
  __shared__ float xch[4][4][16];
  __shared__ float sred[16][64];
  __shared__ float sco[SS];

  const float* w0i0 = wih0 + (size_t)(g0 * DD + d) * 1536;
  const float* w0i1 = wih0 + (size_t)((g0 + 1) * DD + d) * 1536;
  const float* w0h0 = whh0 + (size_t)(g0 * DD + d) * 1024;
  const float* w0h1 = whh0 + (size_t)((g0 + 1) * DD + d) * 1024;
  const float* w1i0 = wih1 + (size_t)(g0 * DD + d) * 1024;
  const float* w1i1 = wih1 + (size_t)((g0 + 1) * DD + d) * 1024;
  const float* w1h0 = whh1 + (size_t)(g0 * DD + d) * 1024;
  const float* w1h1 = whh1 + (size_t)((g0 + 1) * DD + d) * 1024;
  const float b00 = b0[d], b01 = b0[DD + d], b02 = b0[2 * DD + d], b03 = b0[3 * DD + d];
  const float b10 = b1[d], b11 = b1[DD + d], b12 = b1[2 * DD + d], b13 = b1[3 * DD + d];
  const float abv = attn_b[d];
  float c0 = 0.f, c1 = 0.f;

  // ---- prime layer 0: zero input & state -> gates = biases ----
  if (owner && lane < 16) {
    const float cn = sigm(b00) * tanhf(b02);
    c0 = cn;
    stv(h0_all + lane * DD + d, sigm(b03) * tanhf(cn));
  }
  gbar(bar, blk, 32u);
  // ---- prime layer 1: wih1 . h0_all[0] (h1prev = 0) ----
  {
    stagex<1024>(xs, h0_all, tid);
    __syncthreads();
    float a0[8], a1[8];
#pragma unroll
    for (int j = 0; j < 8; ++j) { a0[j] = 0.f; a1[j] = 0.f; }
    gemv_phase<16>(w1i0, w1i1, xs, bh, lane, a0, a1);
    red_xch(a0, a1, xch, dl, g0, bh, lane);
    __syncthreads();
    if (owner && lane < 16) {
      const float si = sigm(xch[dl][0][lane] + b10);
      const float sg = tanhf(xch[dl][2][lane] + b12);
      const float so = sigm(xch[dl][3][lane] + b13);
      const float cn = si * sg;
      c1 = cn;
      stv(c1_all + lane * DD + d, cn);
      stv(h1_all + lane * DD + d, so * tanhf(cn));
    }
  }
  gbar(bar, blk, 32u);

  for (int t = 0; t < TT; ++t) {
    // ===== qW[b,d] = attn_b[d] + c1[b,:].attn_w[d,:1024] =====
    stagex<1024>(xs, c1_all + (size_t)t * (BB * DD), tid);
    __syncthreads();
    {
      float qa[4] = {0.f, 0.f, 0.f, 0.f};
#pragma unroll
      for (int kb = 0; kb < 16; ++kb) {
        const int k = kb * 64 + lane;
        const float wv = attn_w[(size_t)d * 2048 + k];
#pragma unroll
        for (int j = 0; j < 4; ++j) qa[j] = fmaf(wv, xs[sub * 4 + j][k], qa[j]);
      }
#pragma unroll
      for (int j = 0; j < 4; ++j) qa[j] = wred(qa[j]);
      float sel = 0.f;
#pragma unroll
      for (int j = 0; j < 4; ++j)
        if (lane == j) sel = qa[j];
      if (lane < 4) stv(qWbuf + (sub * 4 + lane) * DD + d, sel + abv);
    }
    gbar(bar, blk, 32u);
    // ===== scores: block (b_att, shard), waves 0-7 -> s = shard*8+lw =====
    if (lw < 8) {
      const int s = shard * 8 + lw;
      const float* ew = encWe + ((size_t)(b_att * SS + s)) * DD;
      const float* qb = qWbuf + b_att * DD;
      float a = 0.f;
#pragma unroll
      for (int kb = 0; kb < 16; ++kb) {
        const int k = kb * 64 + lane;
        a += attn_v[k] * tanhf(ldv(qb + k) + ew[k]);
      }
      a = wred(a);
      if (lane == 0) stv(scores_all + (size_t)t * (BB * SS) + b_att * SS + s, a);
    }
    gbar(bar, blk, 32u);
    // ===== softmax + weighted: block (b_att, shard) -> h-cols shard*64..+63 =====
    {
      if (tid < SS) sco[tid] = scores_all[(size_t)t * (BB * SS) + b_att * SS + tid];
      __syncthreads();
      float m = -1e30f;
      for (int s = 0; s < SS; ++s) m = fmaxf(m, sco[s]);
      __syncthreads();
      if (tid < SS) sco[tid] = expf(sco[tid] - m);
      __syncthreads();
      float sum = 0.f;
      for (int s = 0; s < SS; ++s) sum += sco[s];
      const float inv = 1.f / sum;
      float p = 0.f;
#pragma unroll
      for (int i = 0; i < 8; ++i) {
        const int s = lw * 8 + i;
        p += sco[s] * enc_out[((size_t)(b_att * SS + s)) * DD + shard * 64 + lane];
      }
      sred[lw][lane] = p;
      __syncthreads();
      if (lw == 0) {
        float acc = 0.f;
#pragma unroll
        for (int i = 0; i < 16; ++i) acc += sred[i][lane];
        stv(wtd_all + (size_t)t * (BB * DD) + b_att * DD + shard * 64 + lane, acc * inv);
      }
    }
    gbar(bar, blk, 32u);
    // ===== decoder layer 0: K = wtd(1024) | emb(512) | h0prev(1024) =====
    {
      float a0[8], a1[8];
#pragma unroll
      for (int j = 0; j < 8; ++j) { a0[j] = 0.f; a1[j] = 0.f; }
      stagex<1024>(xs, wtd_all + (size_t)t * (BB * DD), tid);
      __syncthreads();
      gemv_phase<16>(w0i0, w0i1, xs, bh, lane, a0, a1);
      __syncthreads();
      stagex<512>(xs, t ? gs_emb + (size_t)(t - 1) * (BB * EE) : zeros, tid);
      __syncthreads();
      gemv_phase<8>(w0i0 + 1024, w0i1 + 1024, xs, bh, lane, a0, a1);
      __syncthreads();
      stagex<1024>(xs, h0_all + (size_t)t * (BB * DD), tid);
      __syncthreads();
      gemv_phase<16>(w0h0, w0h1, xs, bh, lane, a0, a1);
      red_xch(a0, a1, xch, dl, g0, bh, lane);
      __syncthreads();
      if (owner && lane < 16) {
        const float si = sigm(xch[dl][0][lane] + b00);
        const float sf = sigm(xch[dl][1][lane] + b01);
        const float sg = tanhf(xch[dl][2][lane] + b02);
        const float so = sigm(xch[dl][3][lane] + b03);
        const float cn = sf * c0 + si * sg;
        c0 = cn;
        stv(h0_all + (size_t)(t + 1) * (BB * DD) + lane * DD + d, so * tanhf(cn));
      }
    }
    gbar(bar, blk, 32u);
    // ===== decoder layer 1: K = h0new(1024) | h1prev(1024) =====
    {
      float a0[8], a1[8];
#pragma unroll
      for (int j = 0; j < 8; ++j) { a0[j] = 0.f; a1[j] = 0.f; }
      stagex<1024>(xs, h0_all + (size_t)(t + 1) * (BB * DD), tid);
      __syncthreads();
      gemv_phase<16>(w1i0, w1i1, xs, bh, lane, a0, a1);
      __syncthreads();
      stagex<1024>(xs, h1_all + (size_t)t * (BB * DD), tid);
      __syncthreads();
      gemv_phase<16>(w1h0, w1h1, xs, bh, lane, a0, a1);
      red_xch(a0, a1, xch, dl, g0, bh, lane);
      __syncthreads();
      if (owner && lane < 16) {
        const float si = sigm(xch[dl][0][lane] + b10);
        const float sf = sigm(xch[dl][1][lane] + b11);
        const float sg = tanhf(xch[dl][2][lane] + b12);
        const float so = sigm(xch[dl][3][lane] + b13);
        const float cn = sf * c1 + si * sg;
        c1 = cn;
        stv(c1_all + (size_t)(t + 1) * (BB * DD) + lane * DD + d, cn);
        stv(h1_all + (size_t)(t + 1) * (BB * DD) + lane * DD + d, so * tanhf(cn));
      }
    }
    gbar(bar, blk, 32u);
  }
}

// ---- encWe[m][n] = sum_k enc_out[m][k]*attn_w[n][1024+k], LDS-staged X ----
__global__ __launch_bounds__(512) void encwe2_k(const float* __restrict__ enc_out,
                                                const float* __restrict__ attn_w,
                                                float* __restrict__ encWe) {
  const int tid = threadIdx.x, lane = tid & 63, lw = tid >> 6;
  const int mg = blockIdx.x;
  const int nq = blockIdx.y;
  __shared__ float xsl[16][1024];
  for (int i = tid; i < 16 * 1024; i += 512)
    xsl[i >> 10][i & 1023] = enc_out[((size_t)mg * 16 + (i >> 10)) * 1024 + (i & 1023)];
  __syncthreads();
#pragma unroll 1
  for (int nn = 0; nn < 8; ++nn) {
    const int n = nq * 64 + lw * 8 + nn;
    float acc[16];
#pragma unroll
    for (int j = 0; j < 16; ++j) acc[j] = 0.f;
#pragma unroll
    for (int kb = 0; kb < 16; ++kb) {
      const int k = kb * 64 + lane;
      const float wv = attn_w[(size_t)n * 2048 + 1024 + k];
#pragma unroll
      for (int j = 0; j < 16; ++j) acc[j] = fmaf(wv, xsl[j][k], acc[j]);
    }
#pragma unroll
    for (int j = 0; j < 16; ++j) acc[j] = wred(acc[j]);
    float sel = 0.f;
#pragma unroll
    for (int j = 0; j < 16; ++j)
      if (lane == j) sel = acc[j];
    if (lane < 16) encWe[((size_t)mg * 16 + lane) * 1024 + n] = sel;
  }
}

// ---- all logits at the end ----
__global__ void logits_all_k(const float* __restrict__ h1all, const float* __restrict__ out_w,
                             const float* __restrict__ out_b, float* __restrict__ out) {
  const int lane = threadIdx.x & 63;
  const int t = blockIdx.x;
  const int o = blockIdx.y * 4 + (threadIdx.x >> 6);
  const float* h1 = h1all + (size_t)t * (BB * DD);
  float acc[16];
#pragma unroll
  for (int b = 0; b < 16; ++b) acc[b] = 0.f;
  for (int kb = 0; kb < 16; ++kb) {
    const int k = kb * 64 + lane;
    const float wv = out_w[(size_t)o * DD + k];
#pragma unroll
    for (int b = 0; b < 16; ++b) acc[b] = fmaf(wv, h1[b * DD + k], acc[b]);
  }
#pragma unroll
  for (int b = 0; b < 16; ++b) acc[b] = wred(acc[b]);
  float sel = 0.f;
#pragma unroll
  for (int b = 0; b < 16; ++b)
    if (lane == b) sel = acc[b];
  if (lane < 16) out[(size_t)lane * TT * VO + (size_t)t * VO + o] = sel + out_b[o];
}

extern "C" void kernel_launch(void* const* d_in, const int* in_sizes, int n_in,
                              void* d_out, int out_size, void* d_ws, size_t ws_size,
                              hipStream_t stream) {
  const int* x = (const int*)d_in[0];
  const int* gs = (const int*)d_in[1];
  const float* in_emb = (const float*)d_in[2];
  const float* out_emb = (const float*)d_in[3];
  const float* ewih0 = (const float*)d_in[4];
  const float* ewhh0 = (const float*)d_in[5];
  const float* eb0 = (const float*)d_in[6];
  const float* ewih1 = (const float*)d_in[7];
  const float* ewhh1 = (const float*)d_in[8];
  const float* eb1 = (const float*)d_in[9];
  const float* dwih0 = (const float*)d_in[10];
  const float* dwhh0 = (const float*)d_in[11];
  const float* db0 = (const float*)d_in[12];
  const float* dwih1 = (const float*)d_in[13];
  const float* dwhh1 = (const float*)d_in[14];
  const float* db1 = (const float*)d_in[15];
  const float* attn_w = (const float*)d_in[16];
  const float* attn_b = (const float*)d_in[17];
  const float* attn_v = (const float*)d_in[18];
  const float* out_w = (const float*)d_in[19];
  const float* out_b = (const float*)d_in[20];
  float* out = (float*)d_out;

  float* ws = (float*)d_ws;
  size_t off = 0;
  auto alloc = [&](size_t n) { float* p = ws + off; off += n; return p; };
  // ---- memset region (one contiguous memset per call) ----
  unsigned* bar = (unsigned*)alloc(3 * 4096);  // domains: enc d0, enc d1, dec
  float* zeros = alloc(BB * DD);
  float* ehb0 = alloc(2 * 2 * BB * HH);  // enc L0 h ping-pong [slot][dir][b][h]
  float* ehb1 = alloc(2 * 2 * BB * HH);  // enc L1
  const size_t state_n = off;
  // ---- in-kernel fully-written buffers ----
  float* h0_all = alloc((size_t)(TT + 1) * BB * DD);   // write-once per t
  float* h1_all = alloc((size_t)(TT + 1) * BB * DD);
  float* c1_all = alloc((size_t)(TT + 1) * BB * DD);
  float* wtd_all = alloc((size_t)TT * BB * DD);
  float* qWbuf = alloc(BB * DD);
  float* scores_all = alloc((size_t)TT * BB * SS);
  float* xs_emb = alloc((size_t)SS * BB * EE);
  float* gs_emb = alloc((size_t)TT * BB * EE);
  float* l0 = alloc((size_t)SS * BB * (2 * HH));
  float* enc_out = alloc((size_t)BB * SS * (2 * HH));
  float* encWe = alloc((size_t)BB * SS * DD);
  float* gxA = alloc(2ull * 2048ull * 2048ull);  // x-part gates, reused L0/L1
  (void)ws_size; (void)in_sizes; (void)n_in; (void)out_size;

  hipMemsetAsync(d_ws, 0, state_n * sizeof(float), stream);

  gather_k<<<dim3(SS, BB), 128, 0, stream>>>(x, in_emb, xs_emb, SS);
  gather_k<<<dim3(TT, BB), 128, 0, stream>>>(gs, out_emb, gs_emb, TT);

  // encoder layer 0: parallel x-part, then persistent recurrence
  gemv16_k<EE><<<dim3(512, 128, 2), 256, 0, stream>>>(
      xs_emb, EE, ewih0, EE, gxA, 2048, (size_t)4 * HH * EE, 2048ull * 2048ull);
  enc_mega5_k<<<256, 512, 0, stream>>>(gxA, ewhh0, eb0, ehb0, l0, BB * 2 * HH, 2 * HH, bar);
  // encoder layer 1
  gemv16_k<2 * HH><<<dim3(512, 128, 2), 256, 0, stream>>>(
      l0, 2 * HH, ewih1, 2 * HH, gxA, 2048, (size_t)4 * HH * 2 * HH, 2048ull * 2048ull);
  enc_mega5_k<<<256, 512, 0, stream>>>(gxA, ewhh1, eb1, ehb1, enc_out, 2 * HH, SS * 2 * HH,
                                       bar);
  // step-invariant attention term
  encwe2_k<<<dim3(128, 16), 512, 0, stream>>>(enc_out, attn_w, encWe);

  // persistent decoder (prime + 128 steps)
  dec_mega5_k<<<256, 1024, 0, stream>>>(gs_emb, encWe, enc_out, attn_w, attn_b, attn_v,
                                        dwih0, dwhh0, db0, dwih1, dwhh1, db1, zeros,
                                        h0_all, h1_all, c1_all, wtd_all, qWbuf, scores_all,
                                        bar + 2 * 4096);

  // all logits in one parallel launch (h1 slots 1..128)
  logits_all_k<<<dim3(TT, VO / 4), 256, 0, stream>>>(h1_all + BB * DD, out_w, out_b, out);
}

// Round 8
// 17507.294 us; speedup vs baseline: 5.7306x; 1.3778x over previous
//
#include <hip/hip_runtime.h>

#define BB 16
#define SS 128
#define TT 128
#define EE 512
#define HH 512
#define DD 1024
#define VO 10000

#define FMA4(A, W, X)              \
  A = fmaf((W).x, (X).x, A);       \
  A = fmaf((W).y, (X).y, A);       \
  A = fmaf((W).z, (X).z, A);       \
  A = fmaf((W).w, (X).w, A)

__device__ __forceinline__ float wred(float s) {
#pragma unroll
  for (int off = 32; off >= 1; off >>= 1) s += __shfl_xor(s, off, 64);
  return s;
}
__device__ __forceinline__ float sigm(float x) { return 1.f / (1.f + expf(-x)); }

// write-through store (agent-scope relaxed atomic -> bypasses stale-able L2 lines)
__device__ __forceinline__ void stv(float* p, float v) {
  __hip_atomic_store(p, v, __ATOMIC_RELAXED, __HIP_MEMORY_SCOPE_AGENT);
}

// ---- grid barrier: RELAXED monotonic counters, NO acquire (no L2 inv). ----
// Threads drain stores (vmcnt) before arrival; producers write via stv();
// consumers read per-t write-once buffers (first-touch => no stale L2 line).
__device__ __forceinline__ void gbar(unsigned* bar, int lb, unsigned nleaf) {
  asm volatile("s_waitcnt vmcnt(0) lgkmcnt(0)" ::: "memory");
  __syncthreads();
  if (threadIdx.x == 0) {
    unsigned* leaf = bar + ((lb >> 3) << 5);
    unsigned* root = bar + 2048;
    unsigned* gen = bar + 2112;
    const unsigned g = __hip_atomic_load(gen, __ATOMIC_RELAXED, __HIP_MEMORY_SCOPE_AGENT);
    const unsigned a =
        __hip_atomic_fetch_add(leaf, 1u, __ATOMIC_RELAXED, __HIP_MEMORY_SCOPE_AGENT);
    if (a == g * 8u + 7u) {
      const unsigned r =
          __hip_atomic_fetch_add(root, 1u, __ATOMIC_RELAXED, __HIP_MEMORY_SCOPE_AGENT);
      if (r == g * nleaf + (nleaf - 1u))
        __hip_atomic_store(gen, g + 1u, __ATOMIC_RELAXED, __HIP_MEMORY_SCOPE_AGENT);
    }
    while (__hip_atomic_load(gen, __ATOMIC_RELAXED, __HIP_MEMORY_SCOPE_AGENT) == g)
      __builtin_amdgcn_s_sleep(1);
  }
  __syncthreads();
}

// ---- embedding gather (padding_idx=0 -> zeros), out layout [Sn][B][E] ----
__global__ void gather_k(const int* __restrict__ idx, const float* __restrict__ emb,
                         float* __restrict__ out, int Sn) {
  const int s = blockIdx.x, b = blockIdx.y, tid = threadIdx.x;
  const int id = idx[b * Sn + s];
  float4 v = make_float4(0.f, 0.f, 0.f, 0.f);
  if (id != 0) v = ((const float4*)(emb + (size_t)id * EE))[tid];
  ((float4*)(out + ((size_t)s * BB + b) * EE))[tid] = v;
}

// ---- G[z][n][m] = sum_k X[m,k]*W[z,n,k]  (x-part gate GEMMs, float4) ----
template <int K>
__global__ void gemv16b_k(const float* __restrict__ X, int ldx,
                          const float* __restrict__ W, int ldw,
                          float* __restrict__ G, int M, size_t wz, size_t gz) {
  const int lane = threadIdx.x & 63;
  const int n = blockIdx.x * 4 + (threadIdx.x >> 6);
  const int mg = blockIdx.y;
  const int z = blockIdx.z;
  const float* Xr = X + (size_t)mg * 16 * ldx;
  const float* Wn = W + (size_t)z * wz + (size_t)n * ldw;
  float acc[16];
#pragma unroll
  for (int j = 0; j < 16; ++j) acc[j] = 0.f;
#pragma unroll
  for (int it = 0; it < K / 256; ++it) {
    const int k = it * 256 + lane * 4;
    const float4 w4 = *(const float4*)&Wn[k];
#pragma unroll
    for (int j = 0; j < 16; ++j) {
      const float4 xv = *(const float4*)&Xr[(size_t)j * ldx + k];
      FMA4(acc[j], w4, xv);
    }
  }
#pragma unroll
  for (int j = 0; j < 16; ++j) acc[j] = wred(acc[j]);
  float sel = 0.f;
#pragma unroll
  for (int j = 0; j < 16; ++j)
    if (lane == j) sel = acc[j];
  if (lane < 16) G[(size_t)z * gz + (size_t)n * M + mg * 16 + lane] = sel;
}

// ---- persistent encoder: 256 blocks x 512 thr; wave = (d, batch-octet) owns
// all 4 gate rows (regs); h per-t write-once; 1 barrier/step ----
__global__ __launch_bounds__(512, 4) void enc_mega6_k(
    const float* __restrict__ gx, const float* __restrict__ whh,
    const float* __restrict__ bias, float* __restrict__ h_all,  // [SS+1][2][16][512]
    float* __restrict__ seq, int seq_ts, int seq_bs, unsigned* __restrict__ barbase) {
  const int tid = threadIdx.x, lane = tid & 63, lw = tid >> 6;
  const int dir = blockIdx.x >> 7;
  const int lb = blockIdx.x & 127;
  const int w2 = lb * 8 + lw;  // 0..1023
  const int d = w2 >> 1, bq = w2 & 1;
  unsigned* bar = barbase + dir * 4096;

  __shared__ float hs[16][512];

  float wr[4][8];
  const float* wsrc = whh + (size_t)dir * (4 * HH * HH);
#pragma unroll
  for (int g = 0; g < 4; ++g)
#pragma unroll
    for (int j = 0; j < 8; ++j)
      wr[g][j] = wsrc[(size_t)(g * HH + d) * HH + j * 64 + lane];
  float bv[4];
#pragma unroll
  for (int g = 0; g < 4; ++g) bv[g] = bias[dir * 4 * HH + g * HH + d];
  const float* gxz = gx + (size_t)dir * ((size_t)4 * HH * 2048);
  float creg = 0.f;

  for (int t = 0; t < SS; ++t) {
    const int idx = dir ? (SS - 1 - t) : t;
    const float* hp = h_all + ((size_t)t * 2 + dir) * (BB * HH);
    for (int i = tid; i < BB * HH / 4; i += 512)
      *(float4*)&((float*)hs)[i * 4] = *(const float4*)&hp[i * 4];
    __syncthreads();
    float acc[4][8];
#pragma unroll
    for (int g = 0; g < 4; ++g)
#pragma unroll
      for (int j = 0; j < 8; ++j) acc[g][j] = 0.f;
#pragma unroll
    for (int kb = 0; kb < 8; ++kb) {
      const int k = kb * 64 + lane;
#pragma unroll
      for (int j = 0; j < 8; ++j) {
        const float xv = hs[bq * 8 + j][k];
#pragma unroll
        for (int g = 0; g < 4; ++g) acc[g][j] = fmaf(wr[g][kb], xv, acc[g][j]);
      }
    }
#pragma unroll
    for (int g = 0; g < 4; ++g)
#pragma unroll
      for (int j = 0; j < 8; ++j) acc[g][j] = wred(acc[g][j]);
    float s0 = 0.f, s1 = 0.f, s2 = 0.f, s3 = 0.f;
#pragma unroll
    for (int j = 0; j < 8; ++j)
      if (lane == j) { s0 = acc[0][j]; s1 = acc[1][j]; s2 = acc[2][j]; s3 = acc[3][j]; }
    if (lane < 8) {
      const int b = bq * 8 + lane;
      const int m = idx * 16 + b;
      const float gi = sigm(s0 + bv[0] + gxz[(size_t)(0 * HH + d) * 2048 + m]);
      const float gf = sigm(s1 + bv[1] + gxz[(size_t)(1 * HH + d) * 2048 + m]);
      const float gg = tanhf(s2 + bv[2] + gxz[(size_t)(2 * HH + d) * 2048 + m]);
      const float go = sigm(s3 + bv[3] + gxz[(size_t)(3 * HH + d) * 2048 + m]);
      const float cn = gf * creg + gi * gg;
      creg = cn;
      const float hv = go * tanhf(cn);
      stv(h_all + ((size_t)(t + 1) * 2 + dir) * (BB * HH) + b * HH + d, hv);
      seq[(size_t)idx * seq_ts + (size_t)b * seq_bs + dir * HH + d] = hv;
    }
    gbar(bar, lb, 16u);
  }
}

// ---- decoder building blocks ----
template <int CW>
__device__ __forceinline__ void stagex(float (&xs)[16][1024], const float* __restrict__ src,
                                       int tid) {
  for (int i = tid; i < 16 * CW / 4; i += 1024) {
    const int e = i * 4;
    *(float4*)&xs[e / CW][e % CW] = *(const float4*)&src[e];
  }
}

template <int NIT>
__device__ __forceinline__ void gphase(const float* __restrict__ r0,
                                       const float* __restrict__ r1,
                                       const float* __restrict__ r2,
                                       const float* __restrict__ r3,
                                       const float (&xs)[16][1024], int bq, int lane,
                                       float (&acc)[4][4]) {
#pragma unroll
  for (int it = 0; it < NIT; ++it) {
    const int k = it * 256 + lane * 4;
    const float4 w0 = *(const float4*)&r0[k];
    const float4 w1 = *(const float4*)&r1[k];
    const float4 w2 = *(const float4*)&r2[k];
    const float4 w3 = *(const float4*)&r3[k];
#pragma unroll
    for (int j = 0; j < 4; ++j) {
      const float4 xv = *(const float4*)&xs[bq * 4 + j][k];
      FMA4(acc[0][j], w0, xv);
      FMA4(acc[1][j], w1, xv);
      FMA4(acc[2][j], w2, xv);
      FMA4(acc[3][j], w3, xv);
    }
  }
}

__device__ __forceinline__ void wredsel(float (&acc)[4][4], int lane, float (&s)[4]) {
#pragma unroll
  for (int g = 0; g < 4; ++g)
#pragma unroll
    for (int j = 0; j < 4; ++j) acc[g][j] = wred(acc[g][j]);
  s[0] = s[1] = s[2] = s[3] = 0.f;
#pragma unroll
  for (int j = 0; j < 4; ++j)
    if (lane == j) { s[0] = acc[0][j]; s[1] = acc[1][j]; s[2] = acc[2][j]; s[3] = acc[3][j]; }
}

// ---- persistent decoder: 256 blocks x 1024 thr; wave = (d, batch-quad) owns
// all 4 gate rows; float4 weight streaming; per-t write-once state ----
__global__ __launch_bounds__(1024, 4) void dec_mega6_k(
    const float* __restrict__ gs_emb, const float* __restrict__ encWe,
    const float* __restrict__ enc_out, const float* __restrict__ attn_w,
    const float* __restrict__ attn_b, const float* __restrict__ attn_v,
    const float* __restrict__ wih0, const float* __restrict__ whh0,
    const float* __restrict__ b0, const float* __restrict__ wih1,
    const float* __restrict__ whh1, const float* __restrict__ b1,
    const float* __restrict__ zeros, float* __restrict__ h0_all,
    float* __restrict__ h1_all, float* __restrict__ c1_all, float* __restrict__ wtd_all,
    float* __restrict__ qW_all, float* __restrict__ scores_all,
    unsigned* __restrict__ bar) {
  const int tid = threadIdx.x, lane = tid & 63, lw = tid >> 6;
  const int blk = blockIdx.x;
  const int w = blk * 16 + lw;  // 0..4095
  const int d = w >> 2, bq = w & 3;
  const int b_att = blk >> 4, shard = blk & 15;

  __shared__ float xs[16][1024];
  __shared__ float sco[SS];
  __shared__ float sred[16][64];

  const float* w0i0 = wih0 + (size_t)(0 * DD + d) * 1536;
  const float* w0i1 = wih0 + (size_t)(1 * DD + d) * 1536;
  const float* w0i2 = wih0 + (size_t)(2 * DD + d) * 1536;
  const float* w0i3 = wih0 + (size_t)(3 * DD + d) * 1536;
  const float* w0h0 = whh0 + (size_t)(0 * DD + d) * 1024;
  const float* w0h1 = whh0 + (size_t)(1 * DD + d) * 1024;
  const float* w0h2 = whh0 + (size_t)(2 * DD + d) * 1024;
  const float* w0h3 = whh0 + (size_t)(3 * DD + d) * 1024;
  const float* w1i0 = wih1 + (size_t)(0 * DD + d) * 1024;
  const float* w1i1 = wih1 + (size_t)(1 * DD + d) * 1024;
  const float* w1i2 = wih1 + (size_t)(2 * DD + d) * 1024;
  const float* w1i3 = wih1 + (size_t)(3 * DD + d) * 1024;
  const float* w1h0 = whh1 + (size_t)(0 * DD + d) * 1024;
  const float* w1h1 = whh1 + (size_t)(1 * DD + d) * 1024;
  const float* w1h2 = whh1 + (size_t)(2 * DD + d) * 1024;
  const float* w1h3 = whh1 + (size_t)(3 * DD + d) * 1024;
  float bv0[4], bv1[4];
#pragma unroll
  for (int g = 0; g < 4; ++g) { bv0[g] = b0[g * DD + d]; bv1[g] = b1[g * DD + d]; }
  const float abv = attn_b[d];
  float c0 = 0.f, c1 = 0.f;

  // ---- prime layer 0: zero input & state -> gates = biases ----
  if (lane < 4) {
    const float cn = sigm(bv0[0]) * tanhf(bv0[2]);
    c0 = cn;
    stv(h0_all + (bq * 4 + lane) * DD + d, sigm(bv0[3]) * tanhf(cn));
  }
  gbar(bar, blk, 32u);
  // ---- prime layer 1: wih1 . h0_all[0]  (h1prev = 0) ----
  {
    stagex<1024>(xs, h0_all, tid);
    __syncthreads();
    float acc[4][4];
#pragma unroll
    for (int g = 0; g < 4; ++g)
#pragma unroll
      for (int j = 0; j < 4; ++j) acc[g][j] = 0.f;
    gphase<4>(w1i0, w1i1, w1i2, w1i3, xs, bq, lane, acc);
    float s[4];
    wredsel(acc, lane, s);
    if (lane < 4) {
      const int b = bq * 4 + lane;
      const float cn = sigm(s[0] + bv1[0]) * tanhf(s[2] + bv1[2]);
      c1 = cn;
      stv(c1_all + b * DD + d, cn);
      stv(h1_all + b * DD + d, sigm(s[3] + bv1[3]) * tanhf(cn));
    }
  }
  gbar(bar, blk, 32u);

  for (int t = 0; t < TT; ++t) {
    // ===== qW[b,d] = attn_b[d] + c1[b,:].attn_w[d,:1024] =====
    stagex<1024>(xs, c1_all + (size_t)t * (BB * DD), tid);
    __syncthreads();
    {
      float qa[4] = {0.f, 0.f, 0.f, 0.f};
      const float* wq = attn_w + (size_t)d * 2048;
#pragma unroll
      for (int it = 0; it < 4; ++it) {
        const int k = it * 256 + lane * 4;
        const float4 w4 = *(const float4*)&wq[k];
#pragma unroll
        for (int j = 0; j < 4; ++j) {
          const float4 xv = *(const float4*)&xs[bq * 4 + j][k];
          FMA4(qa[j], w4, xv);
        }
      }
#pragma unroll
      for (int j = 0; j < 4; ++j) qa[j] = wred(qa[j]);
      float sel = 0.f;
#pragma unroll
      for (int j = 0; j < 4; ++j)
        if (lane == j) sel = qa[j];
      if (lane < 4)
        stv(qW_all + (size_t)t * (BB * DD) + (bq * 4 + lane) * DD + d, sel + abv);
    }
    gbar(bar, blk, 32u);
    // ===== scores[b_att, shard*8+lw] =====
    if (lw < 8) {
      const int s = shard * 8 + lw;
      const float* ew = encWe + ((size_t)(b_att * SS + s)) * DD;
      const float* qb = qW_all + (size_t)t * (BB * DD) + b_att * DD;
      float a = 0.f;
#pragma unroll
      for (int it = 0; it < 4; ++it) {
        const int k = it * 256 + lane * 4;
        const float4 e4 = *(const float4*)&ew[k];
        const float4 q4 = *(const float4*)&qb[k];
        const float4 v4 = *(const float4*)&attn_v[k];
        a += v4.x * tanhf(q4.x + e4.x) + v4.y * tanhf(q4.y + e4.y) +
             v4.z * tanhf(q4.z + e4.z) + v4.w * tanhf(q4.w + e4.w);
      }
      a = wred(a);
      if (lane == 0) stv(scores_all + (size_t)t * (BB * SS) + b_att * SS + s, a);
    }
    gbar(bar, blk, 32u);
    // ===== softmax + weighted sum -> wtd_all[t][b_att][shard*64+lane] =====
    {
      if (tid < SS) sco[tid] = scores_all[(size_t)t * (BB * SS) + b_att * SS + tid];
      __syncthreads();
      float m = -1e30f;
      for (int s = 0; s < SS; ++s) m = fmaxf(m, sco[s]);
      __syncthreads();
      if (tid < SS) sco[tid] = expf(sco[tid] - m);
      __syncthreads();
      float sum = 0.f;
      for (int s = 0; s < SS; ++s) sum += sco[s];
      const float inv = 1.f / sum;
      float p = 0.f;
#pragma unroll
      for (int i = 0; i < 8; ++i) {
        const int s = lw * 8 + i;
        p += sco[s] * enc_out[((size_t)(b_att * SS + s)) * DD + shard * 64 + lane];
      }
      sred[lw][lane] = p;
      __syncthreads();
      if (lw == 0) {
        float a2 = 0.f;
#pragma unroll
        for (int i = 0; i < 16; ++i) a2 += sred[i][lane];
        stv(wtd_all + (size_t)t * (BB * DD) + b_att * DD + shard * 64 + lane, a2 * inv);
      }
    }
    gbar(bar, blk, 32u);
    // ===== decoder layer 0: K = wtd(1024) | emb(512) | h0prev(1024) =====
    {
      float acc[4][4];
#pragma unroll
      for (int g = 0; g < 4; ++g)
#pragma unroll
        for (int j = 0; j < 4; ++j) acc[g][j] = 0.f;
      stagex<1024>(xs, wtd_all + (size_t)t * (BB * DD), tid);
      __syncthreads();
      gphase<4>(w0i0, w0i1, w0i2, w0i3, xs, bq, lane, acc);
      __syncthreads();
      stagex<512>(xs, t ? gs_emb + (size_t)(t - 1) * (BB * EE) : zeros, tid);
      __syncthreads();
      gphase<2>(w0i0 + 1024, w0i1 + 1024, w0i2 + 1024, w0i3 + 1024, xs, bq, lane, acc);
      __syncthreads();
      stagex<1024>(xs, h0_all + (size_t)t * (BB * DD), tid);
      __syncthreads();
      gphase<4>(w0h0, w0h1, w0h2, w0h3, xs, bq, lane, acc);
      float s[4];
      wredsel(acc, lane, s);
      if (lane < 4) {
        const int b = bq * 4 + lane;
        const float cn = sigm(s[1] + bv0[1]) * c0 + sigm(s[0] + bv0[0]) * tanhf(s[2] + bv0[2]);
        c0 = cn;
        stv(h0_all + (size_t)(t + 1) * (BB * DD) + b * DD + d,
            sigm(s[3] + bv0[3]) * tanhf(cn));
      }
    }
    gbar(bar, blk, 32u);
    // ===== decoder layer 1: K = h0new(1024) | h1prev(1024) =====
    {
      float acc[4][4];
#pragma unroll
      for (int g = 0; g < 4; ++g)
#pragma unroll
        for (int j = 0; j < 4; ++j) acc[g][j] = 0.f;
      stagex<1024>(xs, h0_all + (size_t)(t + 1) * (BB * DD), tid);
      __syncthreads();
      gphase<4>(w1i0, w1i1, w1i2, w1i3, xs, bq, lane, acc);
      __syncthreads();
      stagex<1024>(xs, h1_all + (size_t)t * (BB * DD), tid);
      __syncthreads();
      gphase<4>(w1h0, w1h1, w1h2, w1h3, xs, bq, lane, acc);
      float s[4];
      wredsel(acc, lane, s);
      if (lane < 4) {
        const int b = bq * 4 + lane;
        const float cn = sigm(s[1] + bv1[1]) * c1 + sigm(s[0] + bv1[0]) * tanhf(s[2] + bv1[2]);
        c1 = cn;
        stv(c1_all + (size_t)(t + 1) * (BB * DD) + b * DD + d, cn);
        stv(h1_all + (size_t)(t + 1) * (BB * DD) + b * DD + d,
            sigm(s[3] + bv1[3]) * tanhf(cn));
      }
    }
    gbar(bar, blk, 32u);
  }
}

// ---- encWe[m][n] = sum_k enc_out[m][k]*attn_w[n][1024+k], LDS-staged, float4 ----
__global__ __launch_bounds__(512) void encwe2_k(const float* __restrict__ enc_out,
                                                const float* __restrict__ attn_w,
                                                float* __restrict__ encWe) {
  const int tid = threadIdx.x, lane = tid & 63, lw = tid >> 6;
  const int mg = blockIdx.x;
  const int nq = blockIdx.y;
  __shared__ float xsl[16][1024];
  for (int i = tid; i < 16 * 1024 / 4; i += 512)
    *(float4*)&((float*)xsl)[i * 4] =
        *(const float4*)&enc_out[(size_t)mg * 16 * 1024 + i * 4];
  __syncthreads();
#pragma unroll 1
  for (int nn = 0; nn < 8; ++nn) {
    const int n = nq * 64 + lw * 8 + nn;
    float acc[16];
#pragma unroll
    for (int j = 0; j < 16; ++j) acc[j] = 0.f;
#pragma unroll
    for (int it = 0; it < 4; ++it) {
      const int k = it * 256 + lane * 4;
      const float4 w4 = *(const float4*)&attn_w[(size_t)n * 2048 + 1024 + k];
#pragma unroll
      for (int j = 0; j < 16; ++j) {
        const float4 xv = *(const float4*)&xsl[j][k];
        FMA4(acc[j], w4, xv);
      }
    }
#pragma unroll
    for (int j = 0; j < 16; ++j) acc[j] = wred(acc[j]);
    float sel = 0.f;
#pragma unroll
    for (int j = 0; j < 16; ++j)
      if (lane == j) sel = acc[j];
    if (lane < 16) encWe[((size_t)mg * 16 + lane) * 1024 + n] = sel;
  }
}

// ---- logits: block = (t, 80 o-rows); h1[t] in LDS; 2-row register blocking ----
__global__ __launch_bounds__(1024, 4) void logits2_k(const float* __restrict__ h1all,
                                                     const float* __restrict__ out_w,
                                                     const float* __restrict__ out_b,
                                                     float* __restrict__ out) {
  const int tid = threadIdx.x, lane = tid & 63, lw = tid >> 6;
  const int t = blockIdx.x;
  const int oq = blockIdx.y;  // 0..124
  __shared__ float hs[16][1024];
  const float* h1 = h1all + (size_t)t * (BB * DD);
  for (int i = tid; i < BB * DD / 4; i += 1024)
    *(float4*)&((float*)hs)[i * 4] = *(const float4*)&h1[i * 4];
  __syncthreads();
  const int obase = oq * 80 + lw * 5;
#pragma unroll
  for (int p = 0; p < 3; ++p) {
    const int nr = (p < 2) ? 2 : 1;
    const int o0 = obase + p * 2;
    float accA[16], accB[16];
#pragma unroll
    for (int b = 0; b < 16; ++b) { accA[b] = 0.f; accB[b] = 0.f; }
    const float* wr0 = out_w + (size_t)o0 * DD;
    const float* wr1 = wr0 + DD;
#pragma unroll
    for (int it = 0; it < 4; ++it) {
      const int k = it * 256 + lane * 4;
      const float4 wa = *(const float4*)&wr0[k];
      float4 wb = make_float4(0.f, 0.f, 0.f, 0.f);
      if (nr == 2) wb = *(const float4*)&wr1[k];
#pragma unroll
      for (int b = 0; b < 16; ++b) {
        const float4 xv = *(const float4*)&hs[b][k];
        FMA4(accA[b], wa, xv);
        if (nr == 2) { FMA4(accB[b], wb, xv); }
      }
    }
#pragma unroll
    for (int b = 0; b < 16; ++b) {
      accA[b] = wred(accA[b]);
      if (nr == 2) accB[b] = wred(accB[b]);
    }
    float sA = 0.f, sB = 0.f;
#pragma unroll
    for (int b = 0; b < 16; ++b)
      if (lane == b) { sA = accA[b]; sB = accB[b]; }
    if (lane < 16) {
      out[(size_t)lane * TT * VO + (size_t)t * VO + o0] = sA + out_b[o0];
      if (nr == 2) out[(size_t)lane * TT * VO + (size_t)t * VO + o0 + 1] = sB + out_b[o0 + 1];
    }
  }
}

extern "C" void kernel_launch(void* const* d_in, const int* in_sizes, int n_in,
                              void* d_out, int out_size, void* d_ws, size_t ws_size,
                              hipStream_t stream) {
  const int* x = (const int*)d_in[0];
  const int* gs = (const int*)d_in[1];
  const float* in_emb = (const float*)d_in[2];
  const float* out_emb = (const float*)d_in[3];
  const float* ewih0 = (const float*)d_in[4];
  const float* ewhh0 = (const float*)d_in[5];
  const float* eb0 = (const float*)d_in[6];
  const float* ewih1 = (const float*)d_in[7];
  const float* ewhh1 = (const float*)d_in[8];
  const float* eb1 = (const float*)d_in[9];
  const float* dwih0 = (const float*)d_in[10];
  const float* dwhh0 = (const float*)d_in[11];
  const float* db0 = (const float*)d_in[12];
  const float* dwih1 = (const float*)d_in[13];
  const float* dwhh1 = (const float*)d_in[14];
  const float* db1 = (const float*)d_in[15];
  const float* attn_w = (const float*)d_in[16];
  const float* attn_b = (const float*)d_in[17];
  const float* attn_v = (const float*)d_in[18];
  const float* out_w = (const float*)d_in[19];
  const float* out_b = (const float*)d_in[20];
  float* out = (float*)d_out;

  float* ws = (float*)d_ws;
  size_t off = 0;
  auto alloc = [&](size_t n) { float* p = ws + off; off += n; return p; };
  // ---- memset region: barriers + zeros + enc h_all slot-0s ----
  unsigned* bar = (unsigned*)alloc(3 * 4096);  // domains: enc d0, enc d1, dec
  float* zeros = alloc(BB * DD);
  float* ehA = alloc((size_t)(SS + 1) * 2 * BB * HH);  // enc L0 h_all (all memset'd)
  float* ehB = alloc(2 * BB * HH);                      // enc L1 h_all slot 0
  const size_t state_n = off;
  alloc((size_t)SS * 2 * BB * HH);  // enc L1 h_all slots 1..128 (contiguous w/ ehB)
  // ---- in-kernel write-once / fully-written buffers ----
  float* h0_all = alloc((size_t)(TT + 1) * BB * DD);
  float* h1_all = alloc((size_t)(TT + 1) * BB * DD);
  float* c1_all = alloc((size_t)(TT + 1) * BB * DD);
  float* wtd_all = alloc((size_t)TT * BB * DD);
  float* qW_all = alloc((size_t)TT * BB * DD);
  float* scores_all = alloc((size_t)TT * BB * SS);
  float* xs_emb = alloc((size_t)SS * BB * EE);
  float* gs_emb = alloc((size_t)TT * BB * EE);
  float* l0 = alloc((size_t)SS * BB * (2 * HH));
  float* enc_out = alloc((size_t)BB * SS * (2 * HH));
  float* encWe = alloc((size_t)BB * SS * DD);
  float* gxA = alloc(2ull * 2048ull * 2048ull);  // x-part gates, reused L0/L1
  (void)ws_size; (void)in_sizes; (void)n_in; (void)out_size;

  hipMemsetAsync(d_ws, 0, state_n * sizeof(float), stream);

  gather_k<<<dim3(SS, BB), 128, 0, stream>>>(x, in_emb, xs_emb, SS);
  gather_k<<<dim3(TT, BB), 128, 0, stream>>>(gs, out_emb, gs_emb, TT);

  // encoder layer 0: parallel x-part, then persistent recurrence
  gemv16b_k<EE><<<dim3(512, 128, 2), 256, 0, stream>>>(
      xs_emb, EE, ewih0, EE, gxA, 2048, (size_t)4 * HH * EE, 2048ull * 2048ull);
  enc_mega6_k<<<256, 512, 0, stream>>>(gxA, ewhh0, eb0, ehA, l0, BB * 2 * HH, 2 * HH, bar);
  // encoder layer 1
  gemv16b_k<2 * HH><<<dim3(512, 128, 2), 256, 0, stream>>>(
      l0, 2 * HH, ewih1, 2 * HH, gxA, 2048, (size_t)4 * HH * 2 * HH, 2048ull * 2048ull);
  enc_mega6_k<<<256, 512, 0, stream>>>(gxA, ewhh1, eb1, ehB, enc_out, 2 * HH, SS * 2 * HH,
                                       bar);
  // step-invariant attention term
  encwe2_k<<<dim3(128, 16), 512, 0, stream>>>(enc_out, attn_w, encWe);

  // persistent decoder (prime + 128 steps)
  dec_mega6_k<<<256, 1024, 0, stream>>>(gs_emb, encWe, enc_out, attn_w, attn_b, attn_v,
                                        dwih0, dwhh0, db0, dwih1, dwhh1, db1, zeros,
                                        h0_all, h1_all, c1_all, wtd_all, qW_all,
                                        scores_all, bar + 2 * 4096);

  // all logits (h1 slots 1..128)
  logits2_k<<<dim3(TT, 125), 1024, 0, stream>>>(h1_all + BB * DD, out_w, out_b, out);
}

// Round 9
// 16863.615 us; speedup vs baseline: 5.9493x; 1.0382x over previous
//
#include <hip/hip_runtime.h>

#define BB 16
#define SS 128
#define TT 128
#define EE 512
#define HH 512
#define DD 1024
#define VO 10000

#define FMA4(A, W, X)              \
  A = fmaf((W).x, (X).x, A);       \
  A = fmaf((W).y, (X).y, A);       \
  A = fmaf((W).z, (X).z, A);       \
  A = fmaf((W).w, (X).w, A)

__device__ __forceinline__ float wred(float s) {
#pragma unroll
  for (int off = 32; off >= 1; off >>= 1) s += __shfl_xor(s, off, 64);
  return s;
}
__device__ __forceinline__ float sigm(float x) { return 1.f / (1.f + expf(-x)); }

// write-through store (agent-scope relaxed atomic -> coherence point, no stale L2)
__device__ __forceinline__ void stv(float* p, float v) {
  __hip_atomic_store(p, v, __ATOMIC_RELAXED, __HIP_MEMORY_SCOPE_AGENT);
}

// ---- grid barrier v2: flag-scan, zero atomic-RMW serialization ----
// Each block STORES flag[lb] = target (parallel). Block lb==0 scans all flags
// with its threads in parallel, then releases gen = target; all blocks poll gen.
// All RELAXED agent ops (no L2 invalidation); vmcnt drain before arrival makes
// prior stv() stores visible. Flags monotonic within a launch; domains are
// per-launch so no cross-launch flag reuse. Domain = 16384 uints; gen at 8192.
__device__ __forceinline__ void gbar2(unsigned* bar, int lb, int nblk, unsigned target) {
  asm volatile("s_waitcnt vmcnt(0) lgkmcnt(0)" ::: "memory");
  __syncthreads();
  if (threadIdx.x == 0)
    __hip_atomic_store(bar + lb * 16, target, __ATOMIC_RELAXED, __HIP_MEMORY_SCOPE_AGENT);
  if (lb == 0) {
    for (int i = threadIdx.x; i < nblk; i += blockDim.x)
      while (__hip_atomic_load(bar + i * 16, __ATOMIC_RELAXED, __HIP_MEMORY_SCOPE_AGENT) <
             target)
        __builtin_amdgcn_s_sleep(1);
    __syncthreads();
    if (threadIdx.x == 0)
      __hip_atomic_store(bar + 8192, target, __ATOMIC_RELAXED, __HIP_MEMORY_SCOPE_AGENT);
  }
  if (threadIdx.x == 0)
    while (__hip_atomic_load(bar + 8192, __ATOMIC_RELAXED, __HIP_MEMORY_SCOPE_AGENT) <
           target)
      __builtin_amdgcn_s_sleep(1);
  __syncthreads();
}

// ---- embedding gather (padding_idx=0 -> zeros), out layout [Sn][B][E] ----
__global__ void gather_k(const int* __restrict__ idx, const float* __restrict__ emb,
                         float* __restrict__ out, int Sn) {
  const int s = blockIdx.x, b = blockIdx.y, tid = threadIdx.x;
  const int id = idx[b * Sn + s];
  float4 v = make_float4(0.f, 0.f, 0.f, 0.f);
  if (id != 0) v = ((const float4*)(emb + (size_t)id * EE))[tid];
  ((float4*)(out + ((size_t)s * BB + b) * EE))[tid] = v;
}

// ---- G[z][n][m] = sum_k X[m,k]*W[z,n,k]  (x-part gate GEMMs, float4) ----
template <int K>
__global__ void gemv16b_k(const float* __restrict__ X, int ldx,
                          const float* __restrict__ W, int ldw,
                          float* __restrict__ G, int M, size_t wz, size_t gz) {
  const int lane = threadIdx.x & 63;
  const int n = blockIdx.x * 4 + (threadIdx.x >> 6);
  const int mg = blockIdx.y;
  const int z = blockIdx.z;
  const float* Xr = X + (size_t)mg * 16 * ldx;
  const float* Wn = W + (size_t)z * wz + (size_t)n * ldw;
  float acc[16];
#pragma unroll
  for (int j = 0; j < 16; ++j) acc[j] = 0.f;
#pragma unroll
  for (int it = 0; it < K / 256; ++it) {
    const int k = it * 256 + lane * 4;
    const float4 w4 = *(const float4*)&Wn[k];
#pragma unroll
    for (int j = 0; j < 16; ++j) {
      const float4 xv = *(const float4*)&Xr[(size_t)j * ldx + k];
      FMA4(acc[j], w4, xv);
    }
  }
#pragma unroll
  for (int j = 0; j < 16; ++j) acc[j] = wred(acc[j]);
  float sel = 0.f;
#pragma unroll
  for (int j = 0; j < 16; ++j)
    if (lane == j) sel = acc[j];
  if (lane < 16) G[(size_t)z * gz + (size_t)n * M + mg * 16 + lane] = sel;
}

// ---- persistent encoder: 256 blocks x 512 thr; wave = (d, batch-octet) owns
// all 4 gate rows (regs); h per-t write-once; 1 barrier/step (flag-scan) ----
__global__ __launch_bounds__(512, 4) void enc_mega7_k(
    const float* __restrict__ gx, const float* __restrict__ whh,
    const float* __restrict__ bias, float* __restrict__ h_all,  // [SS+1][2][16][512]
    float* __restrict__ seq, int seq_ts, int seq_bs, unsigned* __restrict__ barbase) {
  const int tid = threadIdx.x, lane = tid & 63, lw = tid >> 6;
  const int dir = blockIdx.x >> 7;
  const int lb = blockIdx.x & 127;
  const int w2 = lb * 8 + lw;  // 0..1023
  const int d = w2 >> 1, bq = w2 & 1;
  unsigned* bar = barbase + dir * 16384;

  __shared__ float hs[16][512];

  float wr[4][8];
  const float* wsrc = whh + (size_t)dir * (4 * HH * HH);
#pragma unroll
  for (int g = 0; g < 4; ++g)
#pragma unroll
    for (int j = 0; j < 8; ++j)
      wr[g][j] = wsrc[(size_t)(g * HH + d) * HH + j * 64 + lane];
  float bv[4];
#pragma unroll
  for (int g = 0; g < 4; ++g) bv[g] = bias[dir * 4 * HH + g * HH + d];
  const float* gxz = gx + (size_t)dir * ((size_t)4 * HH * 2048);
  float creg = 0.f;
  unsigned bt = 0;

  for (int t = 0; t < SS; ++t) {
    const int idx = dir ? (SS - 1 - t) : t;
    const float* hp = h_all + ((size_t)t * 2 + dir) * (BB * HH);
    for (int i = tid; i < BB * HH / 4; i += 512)
      *(float4*)&((float*)hs)[i * 4] = *(const float4*)&hp[i * 4];
    __syncthreads();
    float acc[4][8];
#pragma unroll
    for (int g = 0; g < 4; ++g)
#pragma unroll
      for (int j = 0; j < 8; ++j) acc[g][j] = 0.f;
#pragma unroll
    for (int kb = 0; kb < 8; ++kb) {
      const int k = kb * 64 + lane;
#pragma unroll
      for (int j = 0; j < 8; ++j) {
        const float xv = hs[bq * 8 + j][k];
#pragma unroll
        for (int g = 0; g < 4; ++g) acc[g][j] = fmaf(wr[g][kb], xv, acc[g][j]);
      }
    }
#pragma unroll
    for (int g = 0; g < 4; ++g)
#pragma unroll
      for (int j = 0; j < 8; ++j) acc[g][j] = wred(acc[g][j]);
    float s0 = 0.f, s1 = 0.f, s2 = 0.f, s3 = 0.f;
#pragma unroll
    for (int j = 0; j < 8; ++j)
      if (lane == j) { s0 = acc[0][j]; s1 = acc[1][j]; s2 = acc[2][j]; s3 = acc[3][j]; }
    if (lane < 8) {
      const int b = bq * 8 + lane;
      const int m = idx * 16 + b;
      const float gi = sigm(s0 + bv[0] + gxz[(size_t)(0 * HH + d) * 2048 + m]);
      const float gf = sigm(s1 + bv[1] + gxz[(size_t)(1 * HH + d) * 2048 + m]);
      const float gg = tanhf(s2 + bv[2] + gxz[(size_t)(2 * HH + d) * 2048 + m]);
      const float go = sigm(s3 + bv[3] + gxz[(size_t)(3 * HH + d) * 2048 + m]);
      const float cn = gf * creg + gi * gg;
      creg = cn;
      const float hv = go * tanhf(cn);
      stv(h_all + ((size_t)(t + 1) * 2 + dir) * (BB * HH) + b * HH + d, hv);
      seq[(size_t)idx * seq_ts + (size_t)b * seq_bs + dir * HH + d] = hv;
    }
    gbar2(bar, lb, 128, ++bt);
  }
}

// ---- persistent decoder: 256 blocks x 1024 thr; wave = (d, batch-quad) owns
// all 4 gate rows; DIRECT global float4 x loads (no LDS staging); 5 flag-scan
// barriers/step; per-t write-once state ----
__global__ __launch_bounds__(1024, 4) void dec_mega7_k(
    const float* __restrict__ gs_emb, const float* __restrict__ encWe,
    const float* __restrict__ enc_out, const float* __restrict__ attn_w,
    const float* __restrict__ attn_b, const float* __restrict__ attn_v,
    const float* __restrict__ wih0, const float* __restrict__ whh0,
    const float* __restrict__ b0, const float* __restrict__ wih1,
    const float* __restrict__ whh1, const float* __restrict__ b1,
    const float* __restrict__ zeros, float* __restrict__ h0_all,
    float* __restrict__ h1_all, float* __restrict__ c1_all, float* __restrict__ wtd_all,
    float* __restrict__ qW_all, float* __restrict__ scores_all,
    unsigned* __restrict__ bar) {
  const int tid = threadIdx.x, lane = tid & 63, lw = tid >> 6;
  const int blk = blockIdx.x;
  const int w = blk * 16 + lw;  // 0..4095
  const int d = w >> 2, bq = w & 3;
  const int b_att = blk >> 4, shard = blk & 15;

  __shared__ float sco[SS];
  __shared__ float sred[16][64];

  const float* w0i0 = wih0 + (size_t)(0 * DD + d) * 1536;
  const float* w0i1 = wih0 + (size_t)(1 * DD + d) * 1536;
  const float* w0i2 = wih0 + (size_t)(2 * DD + d) * 1536;
  const float* w0i3 = wih0 + (size_t)(3 * DD + d) * 1536;
  const float* w0h0 = whh0 + (size_t)(0 * DD + d) * 1024;
  const float* w0h1 = whh0 + (size_t)(1 * DD + d) * 1024;
  const float* w0h2 = whh0 + (size_t)(2 * DD + d) * 1024;
  const float* w0h3 = whh0 + (size_t)(3 * DD + d) * 1024;
  const float* w1i0 = wih1 + (size_t)(0 * DD + d) * 1024;
  const float* w1i1 = wih1 + (size_t)(1 * DD + d) * 1024;
  const float* w1i2 = wih1 + (size_t)(2 * DD + d) * 1024;
  const float* w1i3 = wih1 + (size_t)(3 * DD + d) * 1024;
  const float* w1h0 = whh1 + (size_t)(0 * DD + d) * 1024;
  const float* w1h1 = whh1 + (size_t)(1 * DD + d) * 1024;
  const float* w1h2 = whh1 + (size_t)(2 * DD + d) * 1024;
  const float* w1h3 = whh1 + (size_t)(3 * DD + d) * 1024;
  float bv0[4], bv1[4];
#pragma unroll
  for (int g = 0; g < 4; ++g) { bv0[g] = b0[g * DD + d]; bv1[g] = b1[g * DD + d]; }
  const float abv = attn_b[d];
  float c0 = 0.f, c1 = 0.f;
  unsigned bt = 0;

  // ---- prime layer 0: zero input & state -> gates = biases ----
  if (lane < 4) {
    const float cn = sigm(bv0[0]) * tanhf(bv0[2]);
    c0 = cn;
    stv(h0_all + (bq * 4 + lane) * DD + d, sigm(bv0[3]) * tanhf(cn));
  }
  gbar2(bar, blk, 256, ++bt);
  // ---- prime layer 1: wih1 . h0_all[0]  (h1prev = 0) ----
  {
    float acc[4][4];
#pragma unroll
    for (int g = 0; g < 4; ++g)
#pragma unroll
      for (int j = 0; j < 4; ++j) acc[g][j] = 0.f;
#pragma unroll
    for (int it = 0; it < 4; ++it) {
      const int k = it * 256 + lane * 4;
      const float4 q0 = *(const float4*)&w1i0[k];
      const float4 q1 = *(const float4*)&w1i1[k];
      const float4 q2 = *(const float4*)&w1i2[k];
      const float4 q3 = *(const float4*)&w1i3[k];
#pragma unroll
      for (int j = 0; j < 4; ++j) {
        const float4 xv = *(const float4*)&h0_all[(bq * 4 + j) * DD + k];
        FMA4(acc[0][j], q0, xv);
        FMA4(acc[1][j], q1, xv);
        FMA4(acc[2][j], q2, xv);
        FMA4(acc[3][j], q3, xv);
      }
    }
#pragma unroll
    for (int g = 0; g < 4; ++g)
#pragma unroll
      for (int j = 0; j < 4; ++j) acc[g][j] = wred(acc[g][j]);
    float s[4] = {0.f, 0.f, 0.f, 0.f};
#pragma unroll
    for (int j = 0; j < 4; ++j)
      if (lane == j) { s[0] = acc[0][j]; s[1] = acc[1][j]; s[2] = acc[2][j]; s[3] = acc[3][j]; }
    if (lane < 4) {
      const int b = bq * 4 + lane;
      const float cn = sigm(s[0] + bv1[0]) * tanhf(s[2] + bv1[2]);
      c1 = cn;
      stv(c1_all + b * DD + d, cn);
      stv(h1_all + b * DD + d, sigm(s[3] + bv1[3]) * tanhf(cn));
    }
  }
  gbar2(bar, blk, 256, ++bt);

  for (int t = 0; t < TT; ++t) {
    // ===== qW[b,d] = attn_b[d] + c1[b,:].attn_w[d,:1024]  (direct loads) =====
    {
      const float* cb = c1_all + (size_t)t * (BB * DD);
      const float* wq = attn_w + (size_t)d * 2048;
      float qa[4] = {0.f, 0.f, 0.f, 0.f};
#pragma unroll
      for (int it = 0; it < 4; ++it) {
        const int k = it * 256 + lane * 4;
        const float4 w4 = *(const float4*)&wq[k];
#pragma unroll
        for (int j = 0; j < 4; ++j) {
          const float4 xv = *(const float4*)&cb[(bq * 4 + j) * DD + k];
          FMA4(qa[j], w4, xv);
        }
      }
#pragma unroll
      for (int j = 0; j < 4; ++j) qa[j] = wred(qa[j]);
      float sel = 0.f;
#pragma unroll
      for (int j = 0; j < 4; ++j)
        if (lane == j) sel = qa[j];
      if (lane < 4)
        stv(qW_all + (size_t)t * (BB * DD) + (bq * 4 + lane) * DD + d, sel + abv);
    }
    gbar2(bar, blk, 256, ++bt);
    // ===== scores[b_att, shard*8+lw] =====
    if (lw < 8) {
      const int s = shard * 8 + lw;
      const float* ew = encWe + ((size_t)(b_att * SS + s)) * DD;
      const float* qb = qW_all + (size_t)t * (BB * DD) + b_att * DD;
      float a = 0.f;
#pragma unroll
      for (int it = 0; it < 4; ++it) {
        const int k = it * 256 + lane * 4;
        const float4 e4 = *(const float4*)&ew[k];
        const float4 q4 = *(const float4*)&qb[k];
        const float4 v4 = *(const float4*)&attn_v[k];
        a += v4.x * tanhf(q4.x + e4.x) + v4.y * tanhf(q4.y + e4.y) +
             v4.z * tanhf(q4.z + e4.z) + v4.w * tanhf(q4.w + e4.w);
      }
      a = wred(a);
      if (lane == 0) stv(scores_all + (size_t)t * (BB * SS) + b_att * SS + s, a);
    }
    gbar2(bar, blk, 256, ++bt);
    // ===== softmax + weighted sum -> wtd_all[t][b_att][shard*64+lane] =====
    {
      if (tid < SS) sco[tid] = scores_all[(size_t)t * (BB * SS) + b_att * SS + tid];
      __syncthreads();
      float m = -1e30f;
      for (int s = 0; s < SS; ++s) m = fmaxf(m, sco[s]);
      __syncthreads();
      if (tid < SS) sco[tid] = expf(sco[tid] - m);
      __syncthreads();
      float sum = 0.f;
      for (int s = 0; s < SS; ++s) sum += sco[s];
      const float inv = 1.f / sum;
      float p = 0.f;
#pragma unroll
      for (int i = 0; i < 8; ++i) {
        const int s = lw * 8 + i;
        p += sco[s] * enc_out[((size_t)(b_att * SS + s)) * DD + shard * 64 + lane];
      }
      sred[lw][lane] = p;
      __syncthreads();
      if (lw == 0) {
        float a2 = 0.f;
#pragma unroll
        for (int i = 0; i < 16; ++i) a2 += sred[i][lane];
        stv(wtd_all + (size_t)t * (BB * DD) + b_att * DD + shard * 64 + lane, a2 * inv);
      }
    }
    gbar2(bar, blk, 256, ++bt);
    // ===== decoder layer 0: K = wtd(1024) | emb(512) | h0prev(1024) =====
    {
      const float* xw = wtd_all + (size_t)t * (BB * DD);
      const float* em = t ? gs_emb + (size_t)(t - 1) * (BB * EE) : zeros;
      const float* hp = h0_all + (size_t)t * (BB * DD);
      float acc[4][4];
#pragma unroll
      for (int g = 0; g < 4; ++g)
#pragma unroll
        for (int j = 0; j < 4; ++j) acc[g][j] = 0.f;
#pragma unroll
      for (int it = 0; it < 4; ++it) {
        const int k = it * 256 + lane * 4;
        const float4 q0 = *(const float4*)&w0i0[k];
        const float4 q1 = *(const float4*)&w0i1[k];
        const float4 q2 = *(const float4*)&w0i2[k];
        const float4 q3 = *(const float4*)&w0i3[k];
#pragma unroll
        for (int j = 0; j < 4; ++j) {
          const float4 xv = *(const float4*)&xw[(bq * 4 + j) * DD + k];
          FMA4(acc[0][j], q0, xv);
          FMA4(acc[1][j], q1, xv);
          FMA4(acc[2][j], q2, xv);
          FMA4(acc[3][j], q3, xv);
        }
      }
#pragma unroll
      for (int it = 4; it < 6; ++it) {
        const int k = it * 256 + lane * 4;
        const float4 q0 = *(const float4*)&w0i0[k];
        const float4 q1 = *(const float4*)&w0i1[k];
        const float4 q2 = *(const float4*)&w0i2[k];
        const float4 q3 = *(const float4*)&w0i3[k];
#pragma unroll
        for (int j = 0; j < 4; ++j) {
          const float4 xv = *(const float4*)&em[(bq * 4 + j) * EE + (k - 1024)];
          FMA4(acc[0][j], q0, xv);
          FMA4(acc[1][j], q1, xv);
          FMA4(acc[2][j], q2, xv);
          FMA4(acc[3][j], q3, xv);
        }
      }
#pragma unroll
      for (int it = 0; it < 4; ++it) {
        const int k = it * 256 + lane * 4;
        const float4 q0 = *(const float4*)&w0h0[k];
        const float4 q1 = *(const float4*)&w0h1[k];
        const float4 q2 = *(const float4*)&w0h2[k];
        const float4 q3 = *(const float4*)&w0h3[k];
#pragma unroll
        for (int j = 0; j < 4; ++j) {
          const float4 xv = *(const float4*)&hp[(bq * 4 + j) * DD + k];
          FMA4(acc[0][j], q0, xv);
          FMA4(acc[1][j], q1, xv);
          FMA4(acc[2][j], q2, xv);
          FMA4(acc[3][j], q3, xv);
        }
      }
#pragma unroll
      for (int g = 0; g < 4; ++g)
#pragma unroll
        for (int j = 0; j < 4; ++j) acc[g][j] = wred(acc[g][j]);
      float s[4] = {0.f, 0.f, 0.f, 0.f};
#pragma unroll
      for (int j = 0; j < 4; ++j)
        if (lane == j) { s[0] = acc[0][j]; s[1] = acc[1][j]; s[2] = acc[2][j]; s[3] = acc[3][j]; }
      if (lane < 4) {
        const int b = bq * 4 + lane;
        const float cn = sigm(s[1] + bv0[1]) * c0 + sigm(s[0] + bv0[0]) * tanhf(s[2] + bv0[2]);
        c0 = cn;
        stv(h0_all + (size_t)(t + 1) * (BB * DD) + b * DD + d,
            sigm(s[3] + bv0[3]) * tanhf(cn));
      }
    }
    gbar2(bar, blk, 256, ++bt);
    // ===== decoder layer 1: K = h0new(1024) | h1prev(1024) =====
    {
      const float* h0 = h0_all + (size_t)(t + 1) * (BB * DD);
      const float* h1p = h1_all + (size_t)t * (BB * DD);
      float acc[4][4];
#pragma unroll
      for (int g = 0; g < 4; ++g)
#pragma unroll
        for (int j = 0; j < 4; ++j) acc[g][j] = 0.f;
#pragma unroll
      for (int it = 0; it < 4; ++it) {
        const int k = it * 256 + lane * 4;
        const float4 q0 = *(const float4*)&w1i0[k];
        const float4 q1 = *(const float4*)&w1i1[k];
        const float4 q2 = *(const float4*)&w1i2[k];
        const float4 q3 = *(const float4*)&w1i3[k];
#pragma unroll
        for (int j = 0; j < 4; ++j) {
          const float4 xv = *(const float4*)&h0[(bq * 4 + j) * DD + k];
          FMA4(acc[0][j], q0, xv);
          FMA4(acc[1][j], q1, xv);
          FMA4(acc[2][j], q2, xv);
          FMA4(acc[3][j], q3, xv);
        }
      }
#pragma unroll
      for (int it = 0; it < 4; ++it) {
        const int k = it * 256 + lane * 4;
        const float4 q0 = *(const float4*)&w1h0[k];
        const float4 q1 = *(const float4*)&w1h1[k];
        const float4 q2 = *(const float4*)&w1h2[k];
        const float4 q3 = *(const float4*)&w1h3[k];
#pragma unroll
        for (int j = 0; j < 4; ++j) {
          const float4 xv = *(const float4*)&h1p[(bq * 4 + j) * DD + k];
          FMA4(acc[0][j], q0, xv);
          FMA4(acc[1][j], q1, xv);
          FMA4(acc[2][j], q2, xv);
          FMA4(acc[3][j], q3, xv);
        }
      }
#pragma unroll
      for (int g = 0; g < 4; ++g)
#pragma unroll
        for (int j = 0; j < 4; ++j) acc[g][j] = wred(acc[g][j]);
      float s[4] = {0.f, 0.f, 0.f, 0.f};
#pragma unroll
      for (int j = 0; j < 4; ++j)
        if (lane == j) { s[0] = acc[0][j]; s[1] = acc[1][j]; s[2] = acc[2][j]; s[3] = acc[3][j]; }
      if (lane < 4) {
        const int b = bq * 4 + lane;
        const float cn = sigm(s[1] + bv1[1]) * c1 + sigm(s[0] + bv1[0]) * tanhf(s[2] + bv1[2]);
        c1 = cn;
        stv(c1_all + (size_t)(t + 1) * (BB * DD) + b * DD + d, cn);
        stv(h1_all + (size_t)(t + 1) * (BB * DD) + b * DD + d,
            sigm(s[3] + bv1[3]) * tanhf(cn));
      }
    }
    gbar2(bar, blk, 256, ++bt);
  }
}

// ---- encWe[m][n] = sum_k enc_out[m][k]*attn_w[n][1024+k], LDS-staged, float4 ----
__global__ __launch_bounds__(512) void encwe2_k(const float* __restrict__ enc_out,
                                                const float* __restrict__ attn_w,
                                                float* __restrict__ encWe) {
  const int tid = threadIdx.x, lane = tid & 63, lw = tid >> 6;
  const int mg = blockIdx.x;
  const int nq = blockIdx.y;
  __shared__ float xsl[16][1024];
  for (int i = tid; i < 16 * 1024 / 4; i += 512)
    *(float4*)&((float*)xsl)[i * 4] =
        *(const float4*)&enc_out[(size_t)mg * 16 * 1024 + i * 4];
  __syncthreads();
#pragma unroll 1
  for (int nn = 0; nn < 8; ++nn) {
    const int n = nq * 64 + lw * 8 + nn;
    float acc[16];
#pragma unroll
    for (int j = 0; j < 16; ++j) acc[j] = 0.f;
#pragma unroll
    for (int it = 0; it < 4; ++it) {
      const int k = it * 256 + lane * 4;
      const float4 w4 = *(const float4*)&attn_w[(size_t)n * 2048 + 1024 + k];
#pragma unroll
      for (int j = 0; j < 16; ++j) {
        const float4 xv = *(const float4*)&xsl[j][k];
        FMA4(acc[j], w4, xv);
      }
    }
#pragma unroll
    for (int j = 0; j < 16; ++j) acc[j] = wred(acc[j]);
    float sel = 0.f;
#pragma unroll
    for (int j = 0; j < 16; ++j)
      if (lane == j) sel = acc[j];
    if (lane < 16) encWe[((size_t)mg * 16 + lane) * 1024 + n] = sel;
  }
}

// ---- logits: block = (t, 80 o-rows); h1[t] in LDS; 2-row register blocking ----
__global__ __launch_bounds__(1024, 4) void logits2_k(const float* __restrict__ h1all,
                                                     const float* __restrict__ out_w,
                                                     const float* __restrict__ out_b,
                                                     float* __restrict__ out) {
  const int tid = threadIdx.x, lane = tid & 63, lw = tid >> 6;
  const int t = blockIdx.x;
  const int oq = blockIdx.y;  // 0..124
  __shared__ float hs[16][1024];
  const float* h1 = h1all + (size_t)t * (BB * DD);
  for (int i = tid; i < BB * DD / 4; i += 1024)
    *(float4*)&((float*)hs)[i * 4] = *(const float4*)&h1[i * 4];
  __syncthreads();
  const int obase = oq * 80 + lw * 5;
#pragma unroll
  for (int p = 0; p < 3; ++p) {
    const int nr = (p < 2) ? 2 : 1;
    const int o0 = obase + p * 2;
    float accA[16], accB[16];
#pragma unroll
    for (int b = 0; b < 16; ++b) { accA[b] = 0.f; accB[b] = 0.f; }
    const float* wr0 = out_w + (size_t)o0 * DD;
    const float* wr1 = wr0 + DD;
#pragma unroll
    for (int it = 0; it < 4; ++it) {
      const int k = it * 256 + lane * 4;
      const float4 wa = *(const float4*)&wr0[k];
      float4 wb = make_float4(0.f, 0.f, 0.f, 0.f);
      if (nr == 2) wb = *(const float4*)&wr1[k];
#pragma unroll
      for (int b = 0; b < 16; ++b) {
        const float4 xv = *(const float4*)&hs[b][k];
        FMA4(accA[b], wa, xv);
        if (nr == 2) { FMA4(accB[b], wb, xv); }
      }
    }
#pragma unroll
    for (int b = 0; b < 16; ++b) {
      accA[b] = wred(accA[b]);
      if (nr == 2) accB[b] = wred(accB[b]);
    }
    float sA = 0.f, sB = 0.f;
#pragma unroll
    for (int b = 0; b < 16; ++b)
      if (lane == b) { sA = accA[b]; sB = accB[b]; }
    if (lane < 16) {
      out[(size_t)lane * TT * VO + (size_t)t * VO + o0] = sA + out_b[o0];
      if (nr == 2) out[(size_t)lane * TT * VO + (size_t)t * VO + o0 + 1] = sB + out_b[o0 + 1];
    }
  }
}

extern "C" void kernel_launch(void* const* d_in, const int* in_sizes, int n_in,
                              void* d_out, int out_size, void* d_ws, size_t ws_size,
                              hipStream_t stream) {
  const int* x = (const int*)d_in[0];
  const int* gs = (const int*)d_in[1];
  const float* in_emb = (const float*)d_in[2];
  const float* out_emb = (const float*)d_in[3];
  const float* ewih0 = (const float*)d_in[4];
  const float* ewhh0 = (const float*)d_in[5];
  const float* eb0 = (const float*)d_in[6];
  const float* ewih1 = (const float*)d_in[7];
  const float* ewhh1 = (const float*)d_in[8];
  const float* eb1 = (const float*)d_in[9];
  const float* dwih0 = (const float*)d_in[10];
  const float* dwhh0 = (const float*)d_in[11];
  const float* db0 = (const float*)d_in[12];
  const float* dwih1 = (const float*)d_in[13];
  const float* dwhh1 = (const float*)d_in[14];
  const float* db1 = (const float*)d_in[15];
  const float* attn_w = (const float*)d_in[16];
  const float* attn_b = (const float*)d_in[17];
  const float* attn_v = (const float*)d_in[18];
  const float* out_w = (const float*)d_in[19];
  const float* out_b = (const float*)d_in[20];
  float* out = (float*)d_out;

  float* ws = (float*)d_ws;
  size_t off = 0;
  auto alloc = [&](size_t n) { float* p = ws + off; off += n; return p; };
  // ---- memset region: 5 barrier domains + zeros + enc h_all slot-0s ----
  unsigned* bar = (unsigned*)alloc(5 * 16384);  // encL0 d0/d1, encL1 d0/d1, dec
  float* zeros = alloc(BB * DD);
  float* ehA = alloc((size_t)(SS + 1) * 2 * BB * HH);  // enc L0 h_all (all memset'd)
  float* ehB = alloc(2 * BB * HH);                      // enc L1 h_all slot 0
  const size_t state_n = off;
  alloc((size_t)SS * 2 * BB * HH);  // enc L1 h_all slots 1..128 (contiguous w/ ehB)
  // ---- in-kernel write-once / fully-written buffers ----
  float* h0_all = alloc((size_t)(TT + 1) * BB * DD);
  float* h1_all = alloc((size_t)(TT + 1) * BB * DD);
  float* c1_all = alloc((size_t)(TT + 1) * BB * DD);
  float* wtd_all = alloc((size_t)TT * BB * DD);
  float* qW_all = alloc((size_t)TT * BB * DD);
  float* scores_all = alloc((size_t)TT * BB * SS);
  float* xs_emb = alloc((size_t)SS * BB * EE);
  float* gs_emb = alloc((size_t)TT * BB * EE);
  float* l0 = alloc((size_t)SS * BB * (2 * HH));
  float* enc_out = alloc((size_t)BB * SS * (2 * HH));
  float* encWe = alloc((size_t)BB * SS * DD);
  float* gxA = alloc(2ull * 2048ull * 2048ull);  // x-part gates, reused L0/L1
  (void)ws_size; (void)in_sizes; (void)n_in; (void)out_size;

  hipMemsetAsync(d_ws, 0, state_n * sizeof(float), stream);

  gather_k<<<dim3(SS, BB), 128, 0, stream>>>(x, in_emb, xs_emb, SS);
  gather_k<<<dim3(TT, BB), 128, 0, stream>>>(gs, out_emb, gs_emb, TT);

  // encoder layer 0: parallel x-part, then persistent recurrence
  gemv16b_k<EE><<<dim3(512, 128, 2), 256, 0, stream>>>(
      xs_emb, EE, ewih0, EE, gxA, 2048, (size_t)4 * HH * EE, 2048ull * 2048ull);
  enc_mega7_k<<<256, 512, 0, stream>>>(gxA, ewhh0, eb0, ehA, l0, BB * 2 * HH, 2 * HH, bar);
  // encoder layer 1
  gemv16b_k<2 * HH><<<dim3(512, 128, 2), 256, 0, stream>>>(
      l0, 2 * HH, ewih1, 2 * HH, gxA, 2048, (size_t)4 * HH * 2 * HH, 2048ull * 2048ull);
  enc_mega7_k<<<256, 512, 0, stream>>>(gxA, ewhh1, eb1, ehB, enc_out, 2 * HH, SS * 2 * HH,
                                       bar + 2 * 16384);
  // step-invariant attention term
  encwe2_k<<<dim3(128, 16), 512, 0, stream>>>(enc_out, attn_w, encWe);

  // persistent decoder (prime + 128 steps)
  dec_mega7_k<<<256, 1024, 0, stream>>>(gs_emb, encWe, enc_out, attn_w, attn_b, attn_v,
                                        dwih0, dwhh0, db0, dwih1, dwhh1, db1, zeros,
                                        h0_all, h1_all, c1_all, wtd_all, qW_all,
                                        scores_all, bar + 4 * 16384);

  // all logits (h1 slots 1..128)
  logits2_k<<<dim3(TT, 125), 1024, 0, stream>>>(h1_all + BB * DD, out_w, out_b, out);
}